// Round 2
// baseline (7001.925 us; speedup 1.0000x reference)
//
#include <hip/hip_runtime.h>
#include <math.h>

#define NPIX 65536
#define HH 256
#define WW 256
#define DOT_CHUNKS 16

__device__ __forceinline__ float sigmoidf_(float x) { return 1.f / (1.f + __expf(-x)); }
__device__ __forceinline__ float gelu_exact(float x) {
    return 0.5f * x * (1.f + erff(x * 0.70710678118654752f));
}

__global__ void diag_kernel(float* out, float v) {
    if (threadIdx.x == 0 && blockIdx.x == 0) out[0] = v;
}

// ---------------------------------------------------------------------------
// GEMM for 1x1 conv: out[b][o][p] = sum_c w[o][c]*in[b][c][p] (+bias) (+resid)
// block tile: 256 pixels x 64 out-channels. grid: (N/256, Cout/64, nb)
// ---------------------------------------------------------------------------
__global__ __launch_bounds__(256) void gemm1x1(
    const float* __restrict__ in, long inBS,
    const float* __restrict__ w, long wBS,
    const float* __restrict__ bias,
    const float* __restrict__ resid, long resBS,
    float* __restrict__ out, long outBS,
    int Cin, int N)
{
    int b = blockIdx.z;
    int oBase = blockIdx.y * 64;
    int p0 = blockIdx.x * 256 + (threadIdx.x & 31) * 8;
    int og = threadIdx.x >> 5;

    const float* inB = in + (long)b * inBS;
    const float* wB = w + (long)b * wBS;

    __shared__ float wl[64][64];
    float acc[8][8];
#pragma unroll
    for (int i = 0; i < 8; ++i)
#pragma unroll
        for (int j = 0; j < 8; ++j) acc[i][j] = 0.f;

    for (int ck = 0; ck < Cin; ck += 64) {
        __syncthreads();
#pragma unroll
        for (int r = 0; r < 16; ++r) {
            int idx = r * 256 + threadIdx.x;
            int cc = idx >> 6, oo = idx & 63;
            wl[cc][oo] = wB[(long)(oBase + oo) * Cin + ck + cc];
        }
        __syncthreads();
#pragma unroll 4
        for (int c = 0; c < 64; ++c) {
            const float* ip = inB + (long)(ck + c) * N + p0;
            float4 xa = *(const float4*)ip;
            float4 xb = *(const float4*)(ip + 4);
            float4 wa = *(const float4*)(&wl[c][og * 8]);
            float4 wb = *(const float4*)(&wl[c][og * 8 + 4]);
            float xs[8] = {xa.x, xa.y, xa.z, xa.w, xb.x, xb.y, xb.z, xb.w};
            float wv[8] = {wa.x, wa.y, wa.z, wa.w, wb.x, wb.y, wb.z, wb.w};
#pragma unroll
            for (int oi = 0; oi < 8; ++oi)
#pragma unroll
                for (int pj = 0; pj < 8; ++pj)
                    acc[oi][pj] = fmaf(wv[oi], xs[pj], acc[oi][pj]);
        }
    }

#pragma unroll
    for (int oi = 0; oi < 8; ++oi) {
        int o = oBase + og * 8 + oi;
        float bv = bias ? bias[o] : 0.f;
        float res[8] = {0.f, 0.f, 0.f, 0.f, 0.f, 0.f, 0.f, 0.f};
        if (resid) {
            const float* rp = resid + (long)b * resBS + (long)o * N + p0;
            float4 ra = *(const float4*)rp;
            float4 rb = *(const float4*)(rp + 4);
            res[0] = ra.x; res[1] = ra.y; res[2] = ra.z; res[3] = ra.w;
            res[4] = rb.x; res[5] = rb.y; res[6] = rb.z; res[7] = rb.w;
        }
        float v[8];
#pragma unroll
        for (int pj = 0; pj < 8; ++pj) v[pj] = acc[oi][pj] + bv + res[pj];
        float* op = out + (long)b * outBS + (long)o * N + p0;
        *(float4*)op = make_float4(v[0], v[1], v[2], v[3]);
        *(float4*)(op + 4) = make_float4(v[4], v[5], v[6], v[7]);
    }
}

// LayerNorm over 64 channels per pixel. grid (N/256, nb)
__global__ __launch_bounds__(256) void ln64(
    const float* __restrict__ x, const float* __restrict__ w,
    const float* __restrict__ b, float* __restrict__ out, int N)
{
    int bb = blockIdx.y;
    int p = blockIdx.x * 256 + threadIdx.x;
    const float* xb = x + (long)bb * 64 * N + p;
    float s = 0.f, s2 = 0.f;
#pragma unroll
    for (int c = 0; c < 64; ++c) { float v = xb[(long)c * N]; s += v; s2 += v * v; }
    float mu = s * (1.f / 64.f);
    float var = fmaxf(s2 * (1.f / 64.f) - mu * mu, 0.f);
    float inv = rsqrtf(var + 1e-5f);
#pragma unroll
    for (int c = 0; c < 64; ++c) {
        float v = xb[(long)c * N];
        out[((long)bb * 64 + c) * N + p] = (v - mu) * inv * w[c] + b[c];
    }
}

// per-(b,c) reduction over N. grid (C, nb). squared: sum of squares.
__global__ __launch_bounds__(256) void chanreduce(
    const float* __restrict__ in, long bs, float* __restrict__ out,
    int C, int N, float scale, int squared)
{
    int c = blockIdx.x, b = blockIdx.y;
    const float4* p = (const float4*)(in + (long)b * bs + (long)c * N);
    float s = 0.f;
    for (int i = threadIdx.x; i < N / 4; i += 256) {
        float4 v = p[i];
        if (squared) s += v.x * v.x + v.y * v.y + v.z * v.z + v.w * v.w;
        else s += v.x + v.y + v.z + v.w;
    }
    __shared__ float red[256];
    red[threadIdx.x] = s;
    __syncthreads();
    for (int st = 128; st > 0; st >>= 1) {
        if (threadIdx.x < st) red[threadIdx.x] += red[threadIdx.x + st];
        __syncthreads();
    }
    if (threadIdx.x == 0) out[b * C + c] = red[0] * scale;
}

// CIIM grouped dw conv: 384ch concat(fuse[128], la[128], ha[128]) -> 64ch.
// la/ha are spatially constant (means). grid (H, 64, nb), block W.
__global__ __launch_bounds__(256) void ciim_dw(
    const float* __restrict__ fuse, const float* __restrict__ means,
    const float* __restrict__ wdw, const float* __restrict__ bdw,
    float* __restrict__ hl)
{
    int x = threadIdx.x, y = blockIdx.x, c = blockIdx.y, b = blockIdx.z;
    float acc = bdw[c];
#pragma unroll
    for (int j = 0; j < 6; ++j) {
        int ic = 6 * c + j;
        const float* wj = wdw + (c * 6 + j) * 9;
        if (ic < 128) {
            const float* src = fuse + ((long)b * 128 + ic) * NPIX;
#pragma unroll
            for (int ky = 0; ky < 3; ++ky) {
                int yy = y + ky - 1;
                if (yy < 0 || yy >= HH) continue;
#pragma unroll
                for (int kx = 0; kx < 3; ++kx) {
                    int xx = x + kx - 1;
                    if (xx < 0 || xx >= WW) continue;
                    acc += wj[ky * 3 + kx] * src[yy * WW + xx];
                }
            }
        } else {
            float v = means[b * 256 + ic - 128];  // la then ha, contiguous
            float wsum = 0.f;
#pragma unroll
            for (int ky = 0; ky < 3; ++ky) {
                int yy = y + ky - 1;
                if (yy < 0 || yy >= HH) continue;
#pragma unroll
                for (int kx = 0; kx < 3; ++kx) {
                    int xx = x + kx - 1;
                    if (xx < 0 || xx >= WW) continue;
                    wsum += wj[ky * 3 + kx];
                }
            }
            acc += v * wsum;
        }
    }
    hl[((long)b * 64 + c) * NPIX + y * WW + x] = acc;
}

// gating + concat + channel shuffle. grid (N/256, 128, nb)
__global__ __launch_bounds__(256) void outsh_kernel(
    const float* __restrict__ hl, const float* __restrict__ low,
    const float* __restrict__ high, float* __restrict__ out)
{
    int p = blockIdx.x * 256 + threadIdx.x;
    int cn = blockIdx.y, b = blockIdx.z;
    int co = (cn & 31) * 4 + (cn >> 5);  // inverse channel shuffle
    float v;
    if (co < 64) {
        float h = hl[((long)b * 64 + co) * NPIX + p];
        v = sigmoidf_(gelu_exact(h)) * low[((long)b * 64 + co) * NPIX + p];
    } else {
        float h = hl[((long)b * 64 + co - 64) * NPIX + p];
        v = sigmoidf_(fmaxf(h, 0.f)) * high[((long)b * 64 + co - 64) * NPIX + p];
    }
    out[((long)b * 128 + cn) * NPIX + p] = v;
}

// scaled rc2 weights: w'[b][o][c] = w_rc2[o][c] * sigmoid(ecamean[b][c]*eca_w[c])
// grid (nb*32)
__global__ __launch_bounds__(256) void rc2w_build(
    const float* __restrict__ ecam, const float* __restrict__ ecaw,
    const float* __restrict__ wrc2, float* __restrict__ wout)
{
    int idx = blockIdx.x * 256 + threadIdx.x;  // nb*64*128
    int c = idx & 127, o = (idx >> 7) & 63, b = idx >> 13;
    float y = sigmoidf_(ecam[b * 128 + c] * ecaw[c]);
    wout[idx] = wrc2[o * 128 + c] * y;
}

// depthwise 3x3, pad 1. grid (H, C, nb), block W.
__global__ __launch_bounds__(256) void dw3x3(
    const float* __restrict__ in, const float* __restrict__ w,
    float* __restrict__ out, int C)
{
    int x = threadIdx.x, y = blockIdx.x, c = blockIdx.y, b = blockIdx.z;
    const float* src = in + ((long)b * C + c) * NPIX;
    const float* wc = w + c * 9;
    float acc = 0.f;
#pragma unroll
    for (int ky = 0; ky < 3; ++ky) {
        int yy = y + ky - 1;
        if (yy < 0 || yy >= HH) continue;
#pragma unroll
        for (int kx = 0; kx < 3; ++kx) {
            int xx = x + kx - 1;
            if (xx < 0 || xx >= WW) continue;
            acc += wc[ky * 3 + kx] * src[yy * WW + xx];
        }
    }
    out[((long)b * C + c) * NPIX + y * WW + x] = acc;
}

// ffn: fused depthwise 3x3 (256ch) + gelu(y1)*y2 -> 128ch. grid (H, 128, nb)
__global__ __launch_bounds__(256) void ffn_dw_glu(
    const float* __restrict__ y, const float* __restrict__ w,
    float* __restrict__ g)
{
    int x = threadIdx.x, yy0 = blockIdx.x, c = blockIdx.y, b = blockIdx.z;
    const float* s1 = y + ((long)b * 256 + c) * NPIX;
    const float* s2 = y + ((long)b * 256 + c + 128) * NPIX;
    const float* w1 = w + c * 9;
    const float* w2 = w + (c + 128) * 9;
    float a1 = 0.f, a2 = 0.f;
#pragma unroll
    for (int ky = 0; ky < 3; ++ky) {
        int yy = yy0 + ky - 1;
        if (yy < 0 || yy >= HH) continue;
#pragma unroll
        for (int kx = 0; kx < 3; ++kx) {
            int xx = x + kx - 1;
            if (xx < 0 || xx >= WW) continue;
            float wa = w1[ky * 3 + kx], wb = w2[ky * 3 + kx];
            a1 += wa * s1[yy * WW + xx];
            a2 += wb * s2[yy * WW + xx];
        }
    }
    g[((long)b * 128 + c) * NPIX + yy0 * WW + x] = gelu_exact(a1) * a2;
}

// q.k dot products: 64 per (b,h), reduced over N. grid (CHUNKS, 8, nb)
__global__ __launch_bounds__(256) void qk_dot(
    const float* __restrict__ qk, float* __restrict__ part)
{
    int b = blockIdx.z, h = blockIdx.y, chunk = blockIdx.x;
    int lane = threadIdx.x & 63, wave = threadIdx.x >> 6;
    const float* q = qk + (long)b * (192 * NPIX) + (long)(h * 8) * NPIX;
    const float* k = q + (long)64 * NPIX;
    float acc[64];
#pragma unroll
    for (int a = 0; a < 64; ++a) acc[a] = 0.f;
    const int chunkLen = NPIX / DOT_CHUNKS;  // 4096
    int base = chunk * chunkLen + threadIdx.x * 4;
    for (int it = 0; it < chunkLen; it += 1024) {
        int p = base + it;
        float4 qv[8], kv[8];
#pragma unroll
        for (int i = 0; i < 8; ++i) qv[i] = *(const float4*)(q + (long)i * NPIX + p);
#pragma unroll
        for (int j = 0; j < 8; ++j) kv[j] = *(const float4*)(k + (long)j * NPIX + p);
#pragma unroll
        for (int i = 0; i < 8; ++i)
#pragma unroll
            for (int j = 0; j < 8; ++j)
                acc[i * 8 + j] += qv[i].x * kv[j].x + qv[i].y * kv[j].y +
                                  qv[i].z * kv[j].z + qv[i].w * kv[j].w;
    }
#pragma unroll
    for (int a = 0; a < 64; ++a) {
        float v = acc[a];
        v += __shfl_down(v, 32);
        v += __shfl_down(v, 16);
        v += __shfl_down(v, 8);
        v += __shfl_down(v, 4);
        v += __shfl_down(v, 2);
        v += __shfl_down(v, 1);
        if (lane == 0)
            part[((long)((b * 8 + h) * 64 + a)) * (DOT_CHUNKS * 4) + chunk * 4 + wave] = v;
    }
}

// grid (2*nb): nb*512 entries
__global__ __launch_bounds__(256) void qk_reduce(
    const float* __restrict__ part, float* __restrict__ S)
{
    int e = blockIdx.x * 256 + threadIdx.x;
    float s = 0.f;
#pragma unroll
    for (int i = 0; i < DOT_CHUNKS * 4; ++i) s += part[(long)e * (DOT_CHUNKS * 4) + i];
    S[e] = s;
}

// normalize by l2 norms, apply temp, softmax over last dim (8).
// launch: 1 block of 64*nb threads.
__global__ void attn_softmax(
    const float* __restrict__ S, const float* __restrict__ norms,
    const float* __restrict__ temp, float* __restrict__ attn)
{
    int t = threadIdx.x;
    int i = t & 7, h = (t >> 3) & 7, b = t >> 6;
    float nq = fmaxf(sqrtf(norms[b * 128 + h * 8 + i]), 1e-12f);
    float tp = temp[h];
    float row[8];
    float mx = -1e30f;
#pragma unroll
    for (int j = 0; j < 8; ++j) {
        float nk = fmaxf(sqrtf(norms[b * 128 + 64 + h * 8 + j]), 1e-12f);
        row[j] = S[(b * 8 + h) * 64 + i * 8 + j] / (nq * nk) * tp;
        mx = fmaxf(mx, row[j]);
    }
    float sum = 0.f;
#pragma unroll
    for (int j = 0; j < 8; ++j) { row[j] = expf(row[j] - mx); sum += row[j]; }
    float rinv = 1.f / sum;
#pragma unroll
    for (int j = 0; j < 8; ++j) attn[(b * 8 + h) * 64 + i * 8 + j] = row[j] * rinv;
}

// Weff[b][o][cv] = sum_i wproj[o][h*8+i] * attn[b][h][i][j], cv = h*8+j
// grid (64, nb), block 64
__global__ __launch_bounds__(64) void weff_build(
    const float* __restrict__ attn, const float* __restrict__ wproj,
    float* __restrict__ weff)
{
    int cv = threadIdx.x, o = blockIdx.x, b = blockIdx.y;
    int h = cv >> 3, j = cv & 7;
    float s = 0.f;
#pragma unroll
    for (int i = 0; i < 8; ++i)
        s += wproj[o * 64 + h * 8 + i] * attn[(b * 8 + h) * 64 + i * 8 + j];
    weff[((long)b * 64 + o) * 64 + cv] = s;
}

// head conv1: 3x3, 64->32, pad 1, leaky relu. grid (H/4, 2, nb), block 256.
__global__ __launch_bounds__(256) void head_conv1(
    const float* __restrict__ x, const float* __restrict__ w,
    float* __restrict__ out)
{
    int b = blockIdx.z;
    int oBase = blockIdx.y * 16;
    int r = threadIdx.x >> 6;
    int lx = threadIdx.x & 63;
    int y = blockIdx.x * 4 + r;
    int x0 = lx * 4;
    __shared__ float wl[64][9][16];
    for (int idx = threadIdx.x; idx < 64 * 9 * 16; idx += 256) {
        int o = idx & 15, tap = (idx >> 4) % 9, c = idx / 144;
        wl[c][tap][o] = w[((long)(oBase + o) * 64 + c) * 9 + tap];
    }
    __syncthreads();
    float acc[16][4];
#pragma unroll
    for (int o = 0; o < 16; ++o)
#pragma unroll
        for (int px = 0; px < 4; ++px) acc[o][px] = 0.f;

    for (int c = 0; c < 64; ++c) {
        const float* src = x + ((long)b * 64 + c) * NPIX;
        float row[3][6];
#pragma unroll
        for (int ky = 0; ky < 3; ++ky) {
            int yy = y + ky - 1;
            bool yok = (yy >= 0 && yy < HH);
#pragma unroll
            for (int dx = 0; dx < 6; ++dx) {
                int xx = x0 + dx - 1;
                row[ky][dx] = (yok && xx >= 0 && xx < WW) ? src[yy * WW + xx] : 0.f;
            }
        }
#pragma unroll
        for (int ky = 0; ky < 3; ++ky)
#pragma unroll
            for (int kx = 0; kx < 3; ++kx) {
                int tap = ky * 3 + kx;
                float4 w0 = *(const float4*)&wl[c][tap][0];
                float4 w1 = *(const float4*)&wl[c][tap][4];
                float4 w2 = *(const float4*)&wl[c][tap][8];
                float4 w3 = *(const float4*)&wl[c][tap][12];
                float wv[16] = {w0.x, w0.y, w0.z, w0.w, w1.x, w1.y, w1.z, w1.w,
                                w2.x, w2.y, w2.z, w2.w, w3.x, w3.y, w3.z, w3.w};
#pragma unroll
                for (int px = 0; px < 4; ++px) {
                    float xv = row[ky][kx + px];
#pragma unroll
                    for (int o = 0; o < 16; ++o) acc[o][px] = fmaf(wv[o], xv, acc[o][px]);
                }
            }
    }
#pragma unroll
    for (int o = 0; o < 16; ++o) {
        float v[4];
#pragma unroll
        for (int px = 0; px < 4; ++px) {
            float a = acc[o][px];
            v[px] = a > 0.f ? a : 0.01f * a;
        }
        *(float4*)(out + ((long)b * 32 + oBase + o) * NPIX + y * WW + x0) =
            make_float4(v[0], v[1], v[2], v[3]);
    }
}

// head conv2: 3x3, 32->1, pad1, + inp, sigmoid. grid (H, nb), block W.
__global__ __launch_bounds__(256) void head_conv2(
    const float* __restrict__ x, const float* __restrict__ w,
    const float* __restrict__ inp, float* __restrict__ out)
{
    int xx0 = threadIdx.x, y = blockIdx.x, b = blockIdx.y;
    __shared__ float wl[288];
    for (int idx = threadIdx.x; idx < 288; idx += 256) wl[idx] = w[idx];
    __syncthreads();
    float acc = 0.f;
    for (int c = 0; c < 32; ++c) {
        const float* src = x + ((long)b * 32 + c) * NPIX;
#pragma unroll
        for (int ky = 0; ky < 3; ++ky) {
            int yy = y + ky - 1;
            if (yy < 0 || yy >= HH) continue;
#pragma unroll
            for (int kx = 0; kx < 3; ++kx) {
                int xx = xx0 + kx - 1;
                if (xx < 0 || xx >= WW) continue;
                acc += wl[c * 9 + ky * 3 + kx] * src[yy * WW + xx];
            }
        }
    }
    float v = acc + inp[(long)b * NPIX + y * WW + xx0];
    out[(long)b * NPIX + y * WW + xx0] = 1.f / (1.f + expf(-v));
}

// ---------------------------------------------------------------------------
extern "C" void kernel_launch(void* const* d_in, const int* in_sizes, int n_in,
                              void* d_out, int out_size, void* d_ws, size_t ws_size,
                              hipStream_t stream)
{
    const float* inp    = (const float*)d_in[0];
    const float* base   = (const float*)d_in[1];
    const float* detail = (const float*)d_in[2];
    const float* w_ir   = (const float*)d_in[3];
    const float* w_vi   = (const float*)d_in[4];
    const float* w_fu   = (const float*)d_in[5];
    const float* b_fu   = (const float*)d_in[6];
    const float* w_dwc  = (const float*)d_in[7];
    const float* b_dwc  = (const float*)d_in[8];
    const float* eca_w  = (const float*)d_in[9];
    const float* w_rc2  = (const float*)d_in[10];
    const float* ln1w   = (const float*)d_in[11];
    const float* ln1b   = (const float*)d_in[12];
    const float* w_qkv  = (const float*)d_in[13];
    const float* w_qdw  = (const float*)d_in[14];
    const float* temp   = (const float*)d_in[15];
    const float* w_proj = (const float*)d_in[16];
    const float* ln2w   = (const float*)d_in[17];
    const float* ln2b   = (const float*)d_in[18];
    const float* w_in_  = (const float*)d_in[19];
    const float* w_fdw  = (const float*)d_in[20];
    const float* w_out_ = (const float*)d_in[21];
    const float* w_h1   = (const float*)d_in[22];
    const float* w_h2   = (const float*)d_in[23];

    float* out = (float*)d_out;
    float* ws = (float*)d_ws;

    const long N = NPIX;

    // floats needed for nb batches resident at once
    auto needF = [&](long nb) -> size_t {
        size_t big = (size_t)nb * (64 + 64 + 256 + 192) * N;
        size_t small = (size_t)nb * (256 + 128 + 64 * 128 + 128 + 512 * 64 + 512 + 512 + 64 * 64);
        return big + small;
    };

    int bInner;
    if (ws_size >= needF(4) * sizeof(float)) bInner = 4;
    else if (ws_size >= needF(1) * sizeof(float)) bInner = 1;
    else {
        // encode ws_size (in MB) into out[0] so the failure is diagnosable
        diag_kernel<<<1, 64, 0, stream>>>(out, (float)(ws_size >> 20));
        return;
    }

    const long nb = bInner;
    float* X    = ws;
    float* XL   = X + nb * 64 * N;
    float* BUF0 = XL + nb * 64 * N;
    float* BUF1 = BUF0 + nb * 256 * N;
    float* sm   = BUF1 + nb * 192 * N;
    float* means = sm;                        // nb*256
    float* ecam  = means + nb * 256;          // nb*128
    float* rc2w  = ecam + nb * 128;           // nb*64*128
    float* norms = rc2w + nb * 64 * 128;      // nb*128
    float* part  = norms + nb * 128;          // nb*512*64
    float* S     = part + nb * 512 * 64;      // nb*512
    float* attnb = S + nb * 512;              // nb*512
    float* weff  = attnb + nb * 512;          // nb*64*64

    dim3 blk(256);

    for (int b0 = 0; b0 < 4; b0 += bInner) {
        const float* inpB    = inp + (long)b0 * N;
        const float* baseB   = base + (long)b0 * 64 * N;
        const float* detailB = detail + (long)b0 * 64 * N;
        float* out0 = out + (long)b0 * N;
        float* outX0 = out + 262144 + (long)b0 * 64 * N;

        // ---- CIIM ----
        gemm1x1<<<dim3(N / 256, 2, nb), blk, 0, stream>>>(
            baseB, 64 * N, w_ir, 0, nullptr, nullptr, 0, BUF0, 256 * N, 64, N);
        gemm1x1<<<dim3(N / 256, 2, nb), blk, 0, stream>>>(
            detailB, 64 * N, w_vi, 0, nullptr, nullptr, 0, BUF0 + 128 * N, 256 * N, 64, N);
        chanreduce<<<dim3(256, nb), blk, 0, stream>>>(BUF0, 256 * N, means, 256, N, 1.f / N, 0);
        gemm1x1<<<dim3(N / 256, 2, nb), blk, 0, stream>>>(
            BUF0, 256 * N, w_fu, 0, b_fu, nullptr, 0, BUF1, 128 * N, 256, N);
        ciim_dw<<<dim3(HH, 64, nb), blk, 0, stream>>>(BUF1, means, w_dwc, b_dwc, XL);
        outsh_kernel<<<dim3(N / 256, 128, nb), blk, 0, stream>>>(XL, baseB, detailB, BUF0);
        chanreduce<<<dim3(128, nb), blk, 0, stream>>>(BUF0, 128 * N, ecam, 128, N, 1.f / N, 0);
        rc2w_build<<<dim3(nb * 32), blk, 0, stream>>>(ecam, eca_w, w_rc2, rc2w);
        gemm1x1<<<dim3(N / 256, 1, nb), blk, 0, stream>>>(
            BUF0, 128 * N, rc2w, 64 * 128, nullptr, nullptr, 0, X, 64 * N, 128, N);
        hipMemcpyAsync(outX0, X, (size_t)nb * 64 * N * sizeof(float),
                       hipMemcpyDeviceToDevice, stream);

        // ---- transformer blocks ----
        for (int i = 0; i < 4; ++i) {
            // attention
            ln64<<<dim3(N / 256, nb), blk, 0, stream>>>(X, ln1w + i * 64, ln1b + i * 64, XL, N);
            gemm1x1<<<dim3(N / 256, 3, nb), blk, 0, stream>>>(
                XL, 64 * N, w_qkv + (long)i * 192 * 64, 0, nullptr, nullptr, 0,
                BUF0, 192 * N, 64, N);
            dw3x3<<<dim3(HH, 192, nb), blk, 0, stream>>>(
                BUF0, w_qdw + (long)i * 192 * 9, BUF1, 192);
            chanreduce<<<dim3(128, nb), blk, 0, stream>>>(BUF1, 192 * N, norms, 128, N, 1.f, 1);
            qk_dot<<<dim3(DOT_CHUNKS, 8, nb), blk, 0, stream>>>(BUF1, part);
            qk_reduce<<<dim3(2 * nb), blk, 0, stream>>>(part, S);
            attn_softmax<<<dim3(1), dim3(64 * nb), 0, stream>>>(S, norms, temp + i * 8, attnb);
            weff_build<<<dim3(64, nb), dim3(64), 0, stream>>>(
                attnb, w_proj + (long)i * 64 * 64, weff);
            gemm1x1<<<dim3(N / 256, 1, nb), blk, 0, stream>>>(
                BUF1 + 128 * N, 192 * N, weff, 64 * 64, nullptr, X, 64 * N, X, 64 * N, 64, N);
            // ffn
            ln64<<<dim3(N / 256, nb), blk, 0, stream>>>(X, ln2w + i * 64, ln2b + i * 64, XL, N);
            gemm1x1<<<dim3(N / 256, 4, nb), blk, 0, stream>>>(
                XL, 64 * N, w_in_ + (long)i * 256 * 64, 0, nullptr, nullptr, 0,
                BUF0, 256 * N, 64, N);
            ffn_dw_glu<<<dim3(HH, 128, nb), blk, 0, stream>>>(
                BUF0, w_fdw + (long)i * 256 * 9, BUF1);
            gemm1x1<<<dim3(N / 256, 1, nb), blk, 0, stream>>>(
                BUF1, 128 * N, w_out_ + (long)i * 64 * 128, 0, nullptr, X, 64 * N,
                X, 64 * N, 128, N);
        }

        // ---- head ----
        head_conv1<<<dim3(HH / 4, 2, nb), blk, 0, stream>>>(X, w_h1, BUF0);
        head_conv2<<<dim3(HH, nb), blk, 0, stream>>>(BUF0, w_h2, inpB, out0);
    }
}

// Round 3
// 6001.504 us; speedup vs baseline: 1.1667x; 1.1667x over previous
//
#include <hip/hip_runtime.h>
#include <hip/hip_bf16.h>
#include <math.h>

#define NPIX 65536
#define HHH 256
#define WWW 256
#define NP 65536L

typedef unsigned short u16;

__device__ __forceinline__ float bf2f(u16 u) { return __uint_as_float(((unsigned)u) << 16); }
__device__ __forceinline__ u16 f2bf(float f) {
    __hip_bfloat16 h = __float2bfloat16(f);
    return *reinterpret_cast<u16*>(&h);
}
__device__ __forceinline__ float sigmoidf_(float x) { return 1.f / (1.f + __expf(-x)); }
__device__ __forceinline__ float gelu_exact(float x) {
    return 0.5f * x * (1.f + erff(x * 0.70710678118654752f));
}

__global__ void diag_kernel(float* out, float v) {
    if (threadIdx.x == 0 && blockIdx.x == 0) out[0] = v;
}

// ---------------------------------------------------------------------------
// Templated 1x1-conv GEMM. out[b][o][p] = sum_c w[o][c]*in[b][c][p]
// LN: fold LayerNorm of input into epilogue using per-pixel stats computed
//     in-register (requires Cin==64). RESID: add fp32 residual. DUAL: also
//     store fp32 copy to out2. IN_BF16/OUT_BF16: buffer dtypes (fp32 accum).
// block tile: 256 px x 64 out-ch. grid (N/256, Cout/64, nb)
// ---------------------------------------------------------------------------
template<int IN_BF16, int OUT_BF16, int LN, int RESID, int DUAL>
__global__ __launch_bounds__(256) void gemm1x1_t(
    const void* __restrict__ inp, long inBS,
    const float* __restrict__ w, long wBS,
    const float* __restrict__ lnA, const float* __restrict__ lnBc,
    const float* __restrict__ bias,
    const float* __restrict__ resid, long resBS,
    void* __restrict__ outp, long outBS,
    float* __restrict__ out2, long out2BS,
    int Cin, int N)
{
    int b = blockIdx.z;
    int oBase = blockIdx.y * 64;
    int p0 = blockIdx.x * 256 + (threadIdx.x & 31) * 8;
    int og = threadIdx.x >> 5;
    const float* wB = w + (long)b * wBS;
    __shared__ float wl[64][64];
    float acc[8][8];
#pragma unroll
    for (int i = 0; i < 8; ++i)
#pragma unroll
        for (int j = 0; j < 8; ++j) acc[i][j] = 0.f;
    float s[8], s2[8];
    if (LN) {
#pragma unroll
        for (int j = 0; j < 8; ++j) { s[j] = 0.f; s2[j] = 0.f; }
    }
    for (int ck = 0; ck < Cin; ck += 64) {
        __syncthreads();
#pragma unroll
        for (int r = 0; r < 16; ++r) {
            int idx = r * 256 + threadIdx.x;
            int cc = idx >> 6, oo = idx & 63;
            wl[cc][oo] = wB[(long)(oBase + oo) * Cin + ck + cc];
        }
        __syncthreads();
#pragma unroll 4
        for (int c = 0; c < 64; ++c) {
            float xs[8];
            if (IN_BF16) {
                const u16* ip = (const u16*)inp + (long)b * inBS + (long)(ck + c) * N + p0;
                ushort4 ua = *(const ushort4*)ip;
                ushort4 ub = *(const ushort4*)(ip + 4);
                xs[0] = bf2f(ua.x); xs[1] = bf2f(ua.y); xs[2] = bf2f(ua.z); xs[3] = bf2f(ua.w);
                xs[4] = bf2f(ub.x); xs[5] = bf2f(ub.y); xs[6] = bf2f(ub.z); xs[7] = bf2f(ub.w);
            } else {
                const float* ip = (const float*)inp + (long)b * inBS + (long)(ck + c) * N + p0;
                float4 xa = *(const float4*)ip;
                float4 xb = *(const float4*)(ip + 4);
                xs[0] = xa.x; xs[1] = xa.y; xs[2] = xa.z; xs[3] = xa.w;
                xs[4] = xb.x; xs[5] = xb.y; xs[6] = xb.z; xs[7] = xb.w;
            }
            if (LN) {
#pragma unroll
                for (int j = 0; j < 8; ++j) { s[j] += xs[j]; s2[j] = fmaf(xs[j], xs[j], s2[j]); }
            }
            float4 wa = *(const float4*)(&wl[c][og * 8]);
            float4 wb = *(const float4*)(&wl[c][og * 8 + 4]);
            float wv[8] = {wa.x, wa.y, wa.z, wa.w, wb.x, wb.y, wb.z, wb.w};
#pragma unroll
            for (int oi = 0; oi < 8; ++oi)
#pragma unroll
                for (int pj = 0; pj < 8; ++pj)
                    acc[oi][pj] = fmaf(wv[oi], xs[pj], acc[oi][pj]);
        }
    }
    float mu[8], inv[8];
    if (LN) {
#pragma unroll
        for (int j = 0; j < 8; ++j) {
            mu[j] = s[j] * (1.f / 64.f);
            float var = fmaxf(s2[j] * (1.f / 64.f) - mu[j] * mu[j], 0.f);
            inv[j] = rsqrtf(var + 1e-5f);
        }
    }
#pragma unroll
    for (int oi = 0; oi < 8; ++oi) {
        int o = oBase + og * 8 + oi;
        float add0 = bias ? bias[o] : 0.f;
        float Ao = 0.f, Bo = 0.f;
        if (LN) { Ao = lnA[o]; Bo = lnBc[o]; }
        float res[8] = {0, 0, 0, 0, 0, 0, 0, 0};
        if (RESID) {
            const float* rp = resid + (long)b * resBS + (long)o * N + p0;
            float4 ra = *(const float4*)rp;
            float4 rb = *(const float4*)(rp + 4);
            res[0] = ra.x; res[1] = ra.y; res[2] = ra.z; res[3] = ra.w;
            res[4] = rb.x; res[5] = rb.y; res[6] = rb.z; res[7] = rb.w;
        }
        float v[8];
#pragma unroll
        for (int pj = 0; pj < 8; ++pj) {
            float t = acc[oi][pj];
            if (LN) t = inv[pj] * (t - mu[pj] * Ao) + Bo;
            v[pj] = t + add0 + res[pj];
        }
        if (OUT_BF16) {
            u16* op = (u16*)outp + (long)b * outBS + (long)o * N + p0;
            ushort4 o1, o2;
            o1.x = f2bf(v[0]); o1.y = f2bf(v[1]); o1.z = f2bf(v[2]); o1.w = f2bf(v[3]);
            o2.x = f2bf(v[4]); o2.y = f2bf(v[5]); o2.z = f2bf(v[6]); o2.w = f2bf(v[7]);
            *(ushort4*)op = o1; *(ushort4*)(op + 4) = o2;
        } else {
            float* op = (float*)outp + (long)b * outBS + (long)o * N + p0;
            *(float4*)op = make_float4(v[0], v[1], v[2], v[3]);
            *(float4*)(op + 4) = make_float4(v[4], v[5], v[6], v[7]);
        }
        if (DUAL) {
            float* op2 = out2 + (long)b * out2BS + (long)o * N + p0;
            *(float4*)op2 = make_float4(v[0], v[1], v[2], v[3]);
            *(float4*)(op2 + 4) = make_float4(v[4], v[5], v[6], v[7]);
        }
    }
}

// fold LN gamma/beta into qkv and ffn-in weights. grid(28), block 64.
__global__ void fold_ln(
    const float* __restrict__ wqkv, const float* __restrict__ ln1w, const float* __restrict__ ln1b,
    const float* __restrict__ win,  const float* __restrict__ ln2w, const float* __restrict__ ln2b,
    float* __restrict__ fq, float* __restrict__ fqA, float* __restrict__ fqB,
    float* __restrict__ ff, float* __restrict__ ffA, float* __restrict__ ffB)
{
    int g = blockIdx.x;
    int i = g / 7, r = g % 7;
    const float *wsrc, *lg, *lb;
    float *wd, *Ad, *Bd;
    int obase;
    if (r < 3) {
        wsrc = wqkv + (long)i * 192 * 64; lg = ln1w + i * 64; lb = ln1b + i * 64;
        wd = fq + (long)i * 192 * 64; Ad = fqA + i * 192; Bd = fqB + i * 192; obase = r * 64;
    } else {
        wsrc = win + (long)i * 256 * 64; lg = ln2w + i * 64; lb = ln2b + i * 64;
        wd = ff + (long)i * 256 * 64; Ad = ffA + i * 256; Bd = ffB + i * 256; obase = (r - 3) * 64;
    }
    int o = obase + threadIdx.x;
    float A = 0.f, Bv = 0.f;
    for (int c = 0; c < 64; ++c) {
        float wv = wsrc[(long)o * 64 + c];
        float wp = wv * lg[c];
        wd[(long)o * 64 + c] = wp;
        A += wp; Bv += wv * lb[c];
    }
    Ad[o] = A; Bd[o] = Bv;
}

// per-(b,c) mean over N of a bf16 buffer. grid (C, nb)
__global__ __launch_bounds__(256) void chanreduce_bf(
    const u16* __restrict__ in, long bs, float* __restrict__ out,
    int C, int N, float scale)
{
    int c = blockIdx.x, b = blockIdx.y;
    const u16* p = in + (long)b * bs + (long)c * N;
    float s = 0.f;
    for (int i = threadIdx.x * 4; i < N; i += 1024) {
        ushort4 u = *(const ushort4*)(p + i);
        s += bf2f(u.x) + bf2f(u.y) + bf2f(u.z) + bf2f(u.w);
    }
    __shared__ float red[256];
    red[threadIdx.x] = s;
    __syncthreads();
    for (int st = 128; st > 0; st >>= 1) {
        if (threadIdx.x < st) red[threadIdx.x] += red[threadIdx.x + st];
        __syncthreads();
    }
    if (threadIdx.x == 0) out[b * C + c] = red[0] * scale;
}

// stage 6 rows (y0-1..y0+4) of a bf16 channel into S[6][258], zero pads.
__device__ __forceinline__ void stage6(const u16* __restrict__ src, int y0, float (*S)[258])
{
    int tid = threadIdx.x;
#pragma unroll
    for (int j = 0; j < 6; ++j) {
        int row = y0 - 1 + j;
        S[j][tid + 1] = (row >= 0 && row < HHH) ? bf2f(src[row * WWW + tid]) : 0.f;
    }
    if (tid < 6) { S[tid][0] = 0.f; S[tid][257] = 0.f; }
}
__device__ __forceinline__ float dwconv(const float (*S)[258], int col, int r,
                                        const float* __restrict__ w9)
{
    float a = 0.f;
#pragma unroll
    for (int ky = 0; ky < 3; ++ky)
#pragma unroll
        for (int kx = 0; kx < 3; ++kx)
            a = fmaf(w9[ky * 3 + kx], S[r + ky][col + kx], a);
    return a;
}

// fused qkv-dw + l2-sumsq + q.k dots (+ v store). grid (64, 12, nb).
// y<8: head blocks (compute dots+norms for head y). y>=8: v-groups of 16 ch.
__global__ __launch_bounds__(256) void qkv_dw_attn(
    const u16* __restrict__ qkv, long qkvBS,
    const float* __restrict__ wdw,
    u16* __restrict__ vout, long vBS,
    float* __restrict__ S, float* __restrict__ norms)
{
    int rt = blockIdx.x, gy = blockIdx.y, b = blockIdx.z;
    int y0 = rt * 4;
    int tid = threadIdx.x, lane = tid & 63, wave = tid >> 6;
    __shared__ float Sm[6][258];
    __shared__ float red[4][80];
    const u16* base = qkv + (long)b * qkvBS;
    if (gy < 8) {
        int h = gy;
        float qv[8][4], kv[8][4];
#pragma unroll
        for (int j = 0; j < 8; ++j) {
            int c = h * 8 + j;
            __syncthreads();
            stage6(base + (long)c * NP, y0, Sm);
            __syncthreads();
            const float* w9 = wdw + c * 9;
#pragma unroll
            for (int r = 0; r < 4; ++r) qv[j][r] = dwconv(Sm, tid, r, w9);
        }
#pragma unroll
        for (int j = 0; j < 8; ++j) {
            int c = 64 + h * 8 + j;
            __syncthreads();
            stage6(base + (long)c * NP, y0, Sm);
            __syncthreads();
            const float* w9 = wdw + c * 9;
#pragma unroll
            for (int r = 0; r < 4; ++r) kv[j][r] = dwconv(Sm, tid, r, w9);
        }
#pragma unroll
        for (int i = 0; i < 8; ++i) {
#pragma unroll
            for (int j = 0; j < 8; ++j) {
                float d = 0.f;
#pragma unroll
                for (int r = 0; r < 4; ++r) d = fmaf(qv[i][r], kv[j][r], d);
#pragma unroll
                for (int o = 32; o > 0; o >>= 1) d += __shfl_xor(d, o);
                if (lane == 0) red[wave][i * 8 + j] = d;
            }
        }
#pragma unroll
        for (int j = 0; j < 8; ++j) {
            float sq = 0.f, sk = 0.f;
#pragma unroll
            for (int r = 0; r < 4; ++r) {
                sq = fmaf(qv[j][r], qv[j][r], sq);
                sk = fmaf(kv[j][r], kv[j][r], sk);
            }
#pragma unroll
            for (int o = 32; o > 0; o >>= 1) { sq += __shfl_xor(sq, o); sk += __shfl_xor(sk, o); }
            if (lane == 0) { red[wave][64 + j] = sq; red[wave][72 + j] = sk; }
        }
        __syncthreads();
        if (tid < 80) {
            float v = red[0][tid] + red[1][tid] + red[2][tid] + red[3][tid];
            if (tid < 64) atomicAdd(&S[((long)b * 8 + h) * 64 + tid], v);
            else if (tid < 72) atomicAdd(&norms[b * 128 + h * 8 + (tid - 64)], v);
            else atomicAdd(&norms[b * 128 + 64 + h * 8 + (tid - 72)], v);
        }
    } else {
        int cg = (gy - 8) * 16;
#pragma unroll
        for (int j = 0; j < 16; ++j) {
            int c = 128 + cg + j;
            __syncthreads();
            stage6(base + (long)c * NP, y0, Sm);
            __syncthreads();
            const float* w9 = wdw + c * 9;
            u16* dst = vout + (long)b * vBS + (long)(cg + j) * NP;
#pragma unroll
            for (int r = 0; r < 4; ++r) dst[(y0 + r) * WWW + tid] = f2bf(dwconv(Sm, tid, r, w9));
        }
    }
}

// softmax + Weff = wproj x attn. grid (nb), block 64.
__global__ void attn_finalize(
    const float* __restrict__ S, const float* __restrict__ norms,
    const float* __restrict__ temp, const float* __restrict__ wproj,
    float* __restrict__ weff)
{
    int b = blockIdx.x, t = threadIdx.x;
    __shared__ float att[8][8][8];
    {
        int h = t >> 3, iq = t & 7;
        float nq = fmaxf(sqrtf(norms[b * 128 + h * 8 + iq]), 1e-12f);
        float tp = temp[h];
        float row[8], mx = -1e30f;
#pragma unroll
        for (int j = 0; j < 8; ++j) {
            float nk = fmaxf(sqrtf(norms[b * 128 + 64 + h * 8 + j]), 1e-12f);
            row[j] = S[((long)b * 8 + h) * 64 + iq * 8 + j] / (nq * nk) * tp;
            mx = fmaxf(mx, row[j]);
        }
        float sum = 0.f;
#pragma unroll
        for (int j = 0; j < 8; ++j) { row[j] = __expf(row[j] - mx); sum += row[j]; }
        float rinv = 1.f / sum;
#pragma unroll
        for (int j = 0; j < 8; ++j) att[h][iq][j] = row[j] * rinv;
    }
    __syncthreads();
    int o = t;
    for (int cv = 0; cv < 64; ++cv) {
        int h = cv >> 3, j = cv & 7;
        float sws = 0.f;
#pragma unroll
        for (int i = 0; i < 8; ++i) sws = fmaf(wproj[o * 64 + h * 8 + i], att[h][i][j], sws);
        weff[((long)b * 64 + o) * 64 + cv] = sws;
    }
}

// CIIM grouped dw conv (staged). grid (64, 64, nb).
__global__ __launch_bounds__(256) void ciim_dw_s(
    const u16* __restrict__ fuse, long fBS,
    const float* __restrict__ means,
    const float* __restrict__ wdw, const float* __restrict__ bdw,
    u16* __restrict__ hl, long hlBS)
{
    int rt = blockIdx.x, c = blockIdx.y, b = blockIdx.z;
    int y0 = rt * 4, tid = threadIdx.x;
    __shared__ float Sm[6][258];
    float acc[4];
    float bias = bdw[c];
#pragma unroll
    for (int r = 0; r < 4; ++r) acc[r] = bias;
#pragma unroll
    for (int j = 0; j < 6; ++j) {
        int ic = 6 * c + j;
        const float* w9 = wdw + (c * 6 + j) * 9;
        if (ic < 128) {
            __syncthreads();
            stage6(fuse + (long)b * fBS + (long)ic * NP, y0, Sm);
            __syncthreads();
#pragma unroll
            for (int r = 0; r < 4; ++r) acc[r] += dwconv(Sm, tid, r, w9);
        } else {
            float mv = means[b * 256 + ic - 128];
#pragma unroll
            for (int r = 0; r < 4; ++r) {
                int row = y0 + r;
                float ws = 0.f;
#pragma unroll
                for (int ky = 0; ky < 3; ++ky) {
                    int yy = row + ky - 1;
                    if (yy < 0 || yy >= HHH) continue;
#pragma unroll
                    for (int kx = 0; kx < 3; ++kx) {
                        int xx = tid + kx - 1;
                        if (xx < 0 || xx >= WWW) continue;
                        ws += w9[ky * 3 + kx];
                    }
                }
                acc[r] += mv * ws;
            }
        }
    }
    u16* dst = hl + (long)b * hlBS + (long)c * NP;
#pragma unroll
    for (int r = 0; r < 4; ++r) dst[(y0 + r) * WWW + tid] = f2bf(acc[r]);
}

// gating + concat + channel shuffle, 4 px/thread. grid (N/1024, 128, nb)
__global__ __launch_bounds__(256) void outsh4(
    const u16* __restrict__ hl, long hlBS,
    const float* __restrict__ low, long lBS,
    const float* __restrict__ high,
    u16* __restrict__ outb, long oBS)
{
    int p = (blockIdx.x * 256 + threadIdx.x) * 4;
    int cn = blockIdx.y, b = blockIdx.z;
    int co = (cn & 31) * 4 + (cn >> 5);
    const u16* hp;
    const float* sp;
    if (co < 64) {
        hp = hl + (long)b * hlBS + (long)co * NP + p;
        sp = low + (long)b * lBS + (long)co * NP + p;
    } else {
        hp = hl + (long)b * hlBS + (long)(co - 64) * NP + p;
        sp = high + (long)b * lBS + (long)(co - 64) * NP + p;
    }
    ushort4 hu = *(const ushort4*)hp;
    float4 sv = *(const float4*)sp;
    float hv[4] = {bf2f(hu.x), bf2f(hu.y), bf2f(hu.z), bf2f(hu.w)};
    float s4[4] = {sv.x, sv.y, sv.z, sv.w};
    ushort4 ovec;
    u16* ov = (u16*)&ovec;
#pragma unroll
    for (int k = 0; k < 4; ++k) {
        float g = (co < 64) ? sigmoidf_(gelu_exact(hv[k])) : sigmoidf_(fmaxf(hv[k], 0.f));
        ov[k] = f2bf(g * s4[k]);
    }
    *(ushort4*)((u16*)outb + (long)b * oBS + (long)cn * NP + p) = ovec;
}

// scaled rc2 weights. grid (nb*32)
__global__ __launch_bounds__(256) void rc2w_build(
    const float* __restrict__ ecam, const float* __restrict__ ecaw,
    const float* __restrict__ wrc2, float* __restrict__ wout)
{
    int idx = blockIdx.x * 256 + threadIdx.x;
    int c = idx & 127, o = (idx >> 7) & 63, b = idx >> 13;
    float y = sigmoidf_(ecam[b * 128 + c] * ecaw[c]);
    wout[idx] = wrc2[o * 128 + c] * y;
}

// ffn dw + GLU (staged). grid (64, 128, nb)
__global__ __launch_bounds__(256) void ffn_dw_glu_s(
    const u16* __restrict__ y, long yBS,
    const float* __restrict__ w,
    u16* __restrict__ g, long gBS)
{
    int rt = blockIdx.x, c = blockIdx.y, b = blockIdx.z;
    int y0 = rt * 4, tid = threadIdx.x;
    __shared__ float S1[6][258];
    __shared__ float S2[6][258];
    stage6(y + (long)b * yBS + (long)c * NP, y0, S1);
    stage6(y + (long)b * yBS + (long)(c + 128) * NP, y0, S2);
    __syncthreads();
    const float* w1 = w + c * 9;
    const float* w2 = w + (c + 128) * 9;
    u16* dst = g + (long)b * gBS + (long)c * NP;
#pragma unroll
    for (int r = 0; r < 4; ++r) {
        float a1 = dwconv(S1, tid, r, w1);
        float a2 = dwconv(S2, tid, r, w2);
        dst[(y0 + r) * WWW + tid] = f2bf(gelu_exact(a1) * a2);
    }
}

// head conv1: 3x3, 64->32, pad 1, leaky. grid (H/4, 2, nb)
__global__ __launch_bounds__(256) void head_conv1(
    const float* __restrict__ x, const float* __restrict__ w,
    float* __restrict__ out)
{
    int b = blockIdx.z;
    int oBase = blockIdx.y * 16;
    int r = threadIdx.x >> 6;
    int lx = threadIdx.x & 63;
    int y = blockIdx.x * 4 + r;
    int x0 = lx * 4;
    __shared__ float wl[64][9][16];
    for (int idx = threadIdx.x; idx < 64 * 9 * 16; idx += 256) {
        int o = idx & 15, tap = (idx >> 4) % 9, c = idx / 144;
        wl[c][tap][o] = w[((long)(oBase + o) * 64 + c) * 9 + tap];
    }
    __syncthreads();
    float acc[16][4];
#pragma unroll
    for (int o = 0; o < 16; ++o)
#pragma unroll
        for (int px = 0; px < 4; ++px) acc[o][px] = 0.f;

    for (int c = 0; c < 64; ++c) {
        const float* src = x + ((long)b * 64 + c) * NPIX;
        float row[3][6];
#pragma unroll
        for (int ky = 0; ky < 3; ++ky) {
            int yy = y + ky - 1;
            bool yok = (yy >= 0 && yy < HHH);
#pragma unroll
            for (int dx = 0; dx < 6; ++dx) {
                int xx = x0 + dx - 1;
                row[ky][dx] = (yok && xx >= 0 && xx < WWW) ? src[yy * WWW + xx] : 0.f;
            }
        }
#pragma unroll
        for (int ky = 0; ky < 3; ++ky)
#pragma unroll
            for (int kx = 0; kx < 3; ++kx) {
                int tap = ky * 3 + kx;
                float4 w0 = *(const float4*)&wl[c][tap][0];
                float4 w1 = *(const float4*)&wl[c][tap][4];
                float4 w2 = *(const float4*)&wl[c][tap][8];
                float4 w3 = *(const float4*)&wl[c][tap][12];
                float wv[16] = {w0.x, w0.y, w0.z, w0.w, w1.x, w1.y, w1.z, w1.w,
                                w2.x, w2.y, w2.z, w2.w, w3.x, w3.y, w3.z, w3.w};
#pragma unroll
                for (int px = 0; px < 4; ++px) {
                    float xv = row[ky][kx + px];
#pragma unroll
                    for (int o = 0; o < 16; ++o) acc[o][px] = fmaf(wv[o], xv, acc[o][px]);
                }
            }
    }
#pragma unroll
    for (int o = 0; o < 16; ++o) {
        float v[4];
#pragma unroll
        for (int px = 0; px < 4; ++px) {
            float a = acc[o][px];
            v[px] = a > 0.f ? a : 0.01f * a;
        }
        *(float4*)(out + ((long)b * 32 + oBase + o) * NPIX + y * WWW + x0) =
            make_float4(v[0], v[1], v[2], v[3]);
    }
}

// head conv2: 3x3, 32->1, + inp, sigmoid. grid (H, nb)
__global__ __launch_bounds__(256) void head_conv2(
    const float* __restrict__ x, const float* __restrict__ w,
    const float* __restrict__ inp, float* __restrict__ out)
{
    int xx0 = threadIdx.x, y = blockIdx.x, b = blockIdx.y;
    __shared__ float wl[288];
    for (int idx = threadIdx.x; idx < 288; idx += 256) wl[idx] = w[idx];
    __syncthreads();
    float acc = 0.f;
    for (int c = 0; c < 32; ++c) {
        const float* src = x + ((long)b * 32 + c) * NPIX;
#pragma unroll
        for (int ky = 0; ky < 3; ++ky) {
            int yy = y + ky - 1;
            if (yy < 0 || yy >= HHH) continue;
#pragma unroll
            for (int kx = 0; kx < 3; ++kx) {
                int xx = xx0 + kx - 1;
                if (xx < 0 || xx >= WWW) continue;
                acc += wl[c * 9 + ky * 3 + kx] * src[yy * WWW + xx];
            }
        }
    }
    float v = acc + inp[(long)b * NPIX + y * WWW + xx0];
    out[(long)b * NPIX + y * WWW + xx0] = 1.f / (1.f + expf(-v));
}

// ---------------------------------------------------------------------------
extern "C" void kernel_launch(void* const* d_in, const int* in_sizes, int n_in,
                              void* d_out, int out_size, void* d_ws, size_t ws_size,
                              hipStream_t stream)
{
    const float* inp    = (const float*)d_in[0];
    const float* base   = (const float*)d_in[1];
    const float* detail = (const float*)d_in[2];
    const float* w_ir   = (const float*)d_in[3];
    const float* w_vi   = (const float*)d_in[4];
    const float* w_fu   = (const float*)d_in[5];
    const float* b_fu   = (const float*)d_in[6];
    const float* w_dwc  = (const float*)d_in[7];
    const float* b_dwc  = (const float*)d_in[8];
    const float* eca_w  = (const float*)d_in[9];
    const float* w_rc2  = (const float*)d_in[10];
    const float* ln1w   = (const float*)d_in[11];
    const float* ln1b   = (const float*)d_in[12];
    const float* w_qkv  = (const float*)d_in[13];
    const float* w_qdw  = (const float*)d_in[14];
    const float* temp   = (const float*)d_in[15];
    const float* w_proj = (const float*)d_in[16];
    const float* ln2w   = (const float*)d_in[17];
    const float* ln2b   = (const float*)d_in[18];
    const float* w_in_  = (const float*)d_in[19];
    const float* w_fdw  = (const float*)d_in[20];
    const float* w_out_ = (const float*)d_in[21];
    const float* w_h1   = (const float*)d_in[22];
    const float* w_h2   = (const float*)d_in[23];

    float* out = (float*)d_out;
    const long N = NP;

    auto needB = [&](long nb) -> size_t {
        size_t big = (size_t)nb * 64 * N * 4        // X fp32
                   + (size_t)nb * 256 * N * 2       // Y256 bf16
                   + (size_t)nb * 128 * N * 2       // F128 bf16
                   + (size_t)nb * 64 * N * 2;       // V64 bf16
        size_t small = ((size_t)4 * 192 * 64 + 4 * 192 * 2 + (size_t)4 * 256 * 64 + 4 * 256 * 2
                        + nb * (512 + 128) + nb * 256 + nb * 128 + nb * 64 * 128
                        + nb * 64 * 64) * 4 + 1024;
        return big + small;
    };

    int bInner;
    if (ws_size >= needB(4)) bInner = 4;
    else if (ws_size >= needB(1)) bInner = 1;
    else {
        diag_kernel<<<1, 64, 0, stream>>>(out, (float)(ws_size >> 20));
        return;
    }
    const long nb = bInner;

    char* p = (char*)d_ws;
    float* X   = (float*)p;          p += (size_t)nb * 64 * N * 4;
    u16*   Y   = (u16*)p;            p += (size_t)nb * 256 * N * 2;
    u16*   F   = (u16*)p;            p += (size_t)nb * 128 * N * 2;
    u16*   V   = (u16*)p;            p += (size_t)nb * 64 * N * 2;
    float* fq  = (float*)p;          p += (size_t)4 * 192 * 64 * 4;
    float* fqA = (float*)p;          p += 4 * 192 * 4;
    float* fqB = (float*)p;          p += 4 * 192 * 4;
    float* ff  = (float*)p;          p += (size_t)4 * 256 * 64 * 4;
    float* ffA = (float*)p;          p += 4 * 256 * 4;
    float* ffB = (float*)p;          p += 4 * 256 * 4;
    float* Sn  = (float*)p;          p += nb * 640 * 4;   // S (nb*512) + norms (nb*128)
    float* Sd  = Sn;
    float* norms = Sn + nb * 512;
    float* means = (float*)p;        p += nb * 256 * 4;
    float* ecam  = (float*)p;        p += nb * 128 * 4;
    float* rc2w  = (float*)p;        p += (size_t)nb * 64 * 128 * 4;
    float* weff  = (float*)p;        p += (size_t)nb * 64 * 64 * 4;
    float* H32 = (float*)Y;  // head scratch reuses Y (fp32 32ch fits in 256ch bf16)

    dim3 blk(256);
    int Ni = (int)N;

    fold_ln<<<dim3(28), dim3(64), 0, stream>>>(w_qkv, ln1w, ln1b, w_in_, ln2w, ln2b,
                                               fq, fqA, fqB, ff, ffA, ffB);

    for (int b0 = 0; b0 < 4; b0 += bInner) {
        const float* inpB    = inp + (long)b0 * N;
        const float* baseB   = base + (long)b0 * 64 * N;
        const float* detailB = detail + (long)b0 * 64 * N;
        float* out0  = out + (long)b0 * N;
        float* outX0 = out + 262144 + (long)b0 * 64 * N;

        // ---- CIIM ----
        gemm1x1_t<0, 1, 0, 0, 0><<<dim3(256, 2, nb), blk, 0, stream>>>(
            baseB, 64 * N, w_ir, 0, nullptr, nullptr, nullptr, nullptr, 0,
            Y, 256 * N, nullptr, 0, 64, Ni);
        gemm1x1_t<0, 1, 0, 0, 0><<<dim3(256, 2, nb), blk, 0, stream>>>(
            detailB, 64 * N, w_vi, 0, nullptr, nullptr, nullptr, nullptr, 0,
            (void*)(Y + 128 * N), 256 * N, nullptr, 0, 64, Ni);
        chanreduce_bf<<<dim3(256, nb), blk, 0, stream>>>(Y, 256 * N, means, 256, Ni, 1.f / N);
        gemm1x1_t<1, 1, 0, 0, 0><<<dim3(256, 2, nb), blk, 0, stream>>>(
            Y, 256 * N, w_fu, 0, nullptr, nullptr, b_fu, nullptr, 0,
            F, 128 * N, nullptr, 0, 256, Ni);
        ciim_dw_s<<<dim3(64, 64, nb), blk, 0, stream>>>(F, 128 * N, means, w_dwc, b_dwc,
                                                        V, 64 * N);
        outsh4<<<dim3(64, 128, nb), blk, 0, stream>>>(V, 64 * N, baseB, 64 * N, detailB,
                                                      F, 128 * N);
        chanreduce_bf<<<dim3(128, nb), blk, 0, stream>>>(F, 128 * N, ecam, 128, Ni, 1.f / N);
        rc2w_build<<<dim3(nb * 32), blk, 0, stream>>>(ecam, eca_w, w_rc2, rc2w);
        gemm1x1_t<1, 0, 0, 0, 1><<<dim3(256, 1, nb), blk, 0, stream>>>(
            F, 128 * N, rc2w, 64 * 128, nullptr, nullptr, nullptr, nullptr, 0,
            X, 64 * N, outX0, 64 * N, 128, Ni);

        // ---- transformer blocks ----
        for (int i = 0; i < 4; ++i) {
            hipMemsetAsync(Sn, 0, (size_t)nb * 640 * 4, stream);
            gemm1x1_t<0, 1, 1, 0, 0><<<dim3(256, 3, nb), blk, 0, stream>>>(
                X, 64 * N, fq + (long)i * 192 * 64, 0, fqA + i * 192, fqB + i * 192,
                nullptr, nullptr, 0, Y, 256 * N, nullptr, 0, 64, Ni);
            qkv_dw_attn<<<dim3(64, 12, nb), blk, 0, stream>>>(
                Y, 256 * N, w_qdw + (long)i * 192 * 9, V, 64 * N, Sd, norms);
            attn_finalize<<<dim3(nb), dim3(64), 0, stream>>>(
                Sd, norms, temp + i * 8, w_proj + (long)i * 4096, weff);
            gemm1x1_t<1, 0, 0, 1, 0><<<dim3(256, 1, nb), blk, 0, stream>>>(
                V, 64 * N, weff, 4096, nullptr, nullptr, nullptr, X, 64 * N,
                X, 64 * N, nullptr, 0, 64, Ni);
            gemm1x1_t<0, 1, 1, 0, 0><<<dim3(256, 4, nb), blk, 0, stream>>>(
                X, 64 * N, ff + (long)i * 256 * 64, 0, ffA + i * 256, ffB + i * 256,
                nullptr, nullptr, 0, Y, 256 * N, nullptr, 0, 64, Ni);
            ffn_dw_glu_s<<<dim3(64, 128, nb), blk, 0, stream>>>(
                Y, 256 * N, w_fdw + (long)i * 256 * 9, F, 128 * N);
            gemm1x1_t<1, 0, 0, 1, 0><<<dim3(256, 1, nb), blk, 0, stream>>>(
                F, 128 * N, w_out_ + (long)i * 64 * 128, 0, nullptr, nullptr, nullptr,
                X, 64 * N, X, 64 * N, nullptr, 0, 128, Ni);
        }

        // ---- head ----
        head_conv1<<<dim3(64, 2, nb), blk, 0, stream>>>(X, w_h1, H32);
        head_conv2<<<dim3(256, nb), blk, 0, stream>>>(H32, w_h2, inpB, out0);
    }
}

// Round 4
// 3477.930 us; speedup vs baseline: 2.0132x; 1.7256x over previous
//
#include <hip/hip_runtime.h>
#include <hip/hip_bf16.h>
#include <math.h>

#define NP 65536L
#define HHH 256
#define WWW 256
#define QKCH 16

typedef unsigned short u16;
typedef unsigned short ushort8_t __attribute__((ext_vector_type(8)));
typedef short s16x8 __attribute__((ext_vector_type(8)));
typedef float f32x4 __attribute__((ext_vector_type(4)));

__device__ __forceinline__ float bf2f(u16 u) { return __uint_as_float(((unsigned)u) << 16); }
__device__ __forceinline__ u16 f2bf(float f) {
    __hip_bfloat16 h = __float2bfloat16(f);
    return *reinterpret_cast<u16*>(&h);
}
__device__ __forceinline__ float sigmoidf_(float x) { return 1.f / (1.f + __expf(-x)); }
__device__ __forceinline__ float gelu_exact(float x) {
    return 0.5f * x * (1.f + erff(x * 0.70710678118654752f));
}

__global__ void diag_kernel(float* out, float v) {
    if (threadIdx.x == 0 && blockIdx.x == 0) out[0] = v;
}

// fp32 -> bf16 bulk convert (n multiple of 4; grid = n/1024)
__global__ __launch_bounds__(256) void cvt_f2b(const float* __restrict__ src,
                                               u16* __restrict__ dst, long n)
{
    long i = ((long)blockIdx.x * 256 + threadIdx.x) * 4;
    if (i >= n) return;
    float4 v = *(const float4*)(src + i);
    ushort4 o;
    o.x = f2bf(v.x); o.y = f2bf(v.y); o.z = f2bf(v.z); o.w = f2bf(v.w);
    *(ushort4*)(dst + i) = o;
}

// ---------------------------------------------------------------------------
// MFMA bf16 GEMM for 1x1 conv: out[b][o][p] = sum_c w[o][c] * in[b][c][p]
// block: 256 thr = 4 waves; tile M=64 o x N=256 px; K chunks of 64.
// LDS: XT transposed [px][c] (pad 8) so B-frag = one ds_read_b128.
// grid (M/64, 256, nb)
// ---------------------------------------------------------------------------
template<int OUT_BF16, int RESID, int DUAL, int BIAS>
__global__ __launch_bounds__(256) void gemm_mfma(
    const u16* __restrict__ in, long inBS,
    const u16* __restrict__ wbf, long wBS,
    const float* __restrict__ bias,
    const float* __restrict__ resid, long resBS,
    void* __restrict__ outp, long outBS,
    float* __restrict__ out2, long out2BS,
    int Cin)
{
    __shared__ u16 XT[256][72];
    __shared__ u16 WT[64][72];
    int b = blockIdx.z;
    int oBase = blockIdx.x * 64;
    long P0 = (long)blockIdx.y * 256;
    int tid = threadIdx.x;
    int lane = tid & 63, wave = tid >> 6;
    const u16* inB = in + (long)b * inBS;
    const u16* wB = wbf + (long)b * wBS;

    f32x4 acc[4][4];
#pragma unroll
    for (int m = 0; m < 4; ++m)
#pragma unroll
        for (int n = 0; n < 4; ++n) acc[m][n] = (f32x4){0.f, 0.f, 0.f, 0.f};

    for (int ck = 0; ck < Cin; ck += 64) {
        if (ck) __syncthreads();
        {   // stage weights chunk [64 o][64 c]
            int o = tid >> 2, cs = (tid & 3) * 16;
            const u16* src = wB + (long)(oBase + o) * Cin + ck + cs;
            ushort8_t w0 = *(const ushort8_t*)src;
            ushort8_t w1 = *(const ushort8_t*)(src + 8);
            *(ushort8_t*)&WT[o][cs] = w0;
            *(ushort8_t*)&WT[o][cs + 8] = w1;
        }
        {   // stage X chunk transposed: [256 px][64 c]
            int c0 = (tid & 7) * 8;
            int pt = (tid >> 3) * 8;
            ushort8_t r[8];
#pragma unroll
            for (int i = 0; i < 8; ++i)
                r[i] = *(const ushort8_t*)(inB + (long)(ck + c0 + i) * NP + P0 + pt);
#pragma unroll
            for (int j = 0; j < 8; ++j) {
                ushort8_t v;
#pragma unroll
                for (int i = 0; i < 8; ++i) v[i] = r[i][j];
                *(ushort8_t*)&XT[pt + j][c0] = v;
            }
        }
        __syncthreads();
        int rl = lane & 15;
#pragma unroll
        for (int ks = 0; ks < 2; ++ks) {
            int kc = ks * 32 + (lane >> 4) * 8;
            s16x8 a[4], bb[4];
#pragma unroll
            for (int m = 0; m < 4; ++m)
                a[m] = *(const s16x8*)&WT[m * 16 + rl][kc];
#pragma unroll
            for (int n = 0; n < 4; ++n)
                bb[n] = *(const s16x8*)&XT[wave * 64 + n * 16 + rl][kc];
#pragma unroll
            for (int m = 0; m < 4; ++m)
#pragma unroll
                for (int n = 0; n < 4; ++n)
                    acc[m][n] = __builtin_amdgcn_mfma_f32_16x16x32_bf16(
                        a[m], bb[n], acc[m][n], 0, 0, 0);
        }
    }
    // epilogue: D col = lane&15 (pixel), row = (lane>>4)*4 + reg (o)
    int rl = lane & 15, rg = lane >> 4;
#pragma unroll
    for (int m = 0; m < 4; ++m) {
        int o0 = oBase + m * 16 + rg * 4;
#pragma unroll
        for (int n = 0; n < 4; ++n) {
            long px = P0 + wave * 64 + n * 16 + rl;
#pragma unroll
            for (int r = 0; r < 4; ++r) {
                int oo = o0 + r;
                float v = acc[m][n][r];
                if (BIAS) v += bias[oo];
                if (RESID) v += resid[(long)b * resBS + (long)oo * NP + px];
                if (OUT_BF16) ((u16*)outp)[(long)b * outBS + (long)oo * NP + px] = f2bf(v);
                else ((float*)outp)[(long)b * outBS + (long)oo * NP + px] = v;
                if (DUAL) out2[(long)b * out2BS + (long)oo * NP + px] = v;
            }
        }
    }
}

// LN standardize pre-pass: XN = (X - mu)/sqrt(var+eps), bf16. grid (256, nb)
__global__ __launch_bounds__(256) void ln_norm(
    const float* __restrict__ X, u16* __restrict__ XN)
{
    int b = blockIdx.y;
    long p = (long)blockIdx.x * 256 + threadIdx.x;
    const float* xb = X + (long)b * 64 * NP + p;
    float x[64];
    float s = 0.f, s2 = 0.f;
#pragma unroll
    for (int c = 0; c < 64; ++c) {
        x[c] = xb[(long)c * NP];
        s += x[c]; s2 = fmaf(x[c], x[c], s2);
    }
    float mu = s * (1.f / 64.f);
    float var = fmaxf(s2 * (1.f / 64.f) - mu * mu, 0.f);
    float inv = rsqrtf(var + 1e-5f);
    u16* xo = XN + (long)b * 64 * NP + p;
#pragma unroll
    for (int c = 0; c < 64; ++c) xo[(long)c * NP] = f2bf((x[c] - mu) * inv);
}

// fold LN gamma/beta into qkv / ffn-in weights; bf16 weights + fp32 bias.
__global__ void fold_ln(
    const float* __restrict__ wqkv, const float* __restrict__ ln1w, const float* __restrict__ ln1b,
    const float* __restrict__ win,  const float* __restrict__ ln2w, const float* __restrict__ ln2b,
    u16* __restrict__ fq, float* __restrict__ fqB,
    u16* __restrict__ ff, float* __restrict__ ffB)
{
    int g = blockIdx.x;
    int i = g / 7, r = g % 7;
    const float *wsrc, *lg, *lb;
    u16* wd; float* Bd;
    int obase;
    if (r < 3) {
        wsrc = wqkv + (long)i * 192 * 64; lg = ln1w + i * 64; lb = ln1b + i * 64;
        wd = fq + (long)i * 192 * 64; Bd = fqB + i * 192; obase = r * 64;
    } else {
        wsrc = win + (long)i * 256 * 64; lg = ln2w + i * 64; lb = ln2b + i * 64;
        wd = ff + (long)i * 256 * 64; Bd = ffB + i * 256; obase = (r - 3) * 64;
    }
    int o = obase + threadIdx.x;
    float Bv = 0.f;
    for (int c = 0; c < 64; ++c) {
        float wv = wsrc[(long)o * 64 + c];
        wd[(long)o * 64 + c] = f2bf(wv * lg[c]);
        Bv += wv * lb[c];
    }
    Bd[o] = Bv;
}

// per-(b,c) mean of bf16 buffer. grid (C, nb)
__global__ __launch_bounds__(256) void chanreduce_bf(
    const u16* __restrict__ in, long bs, float* __restrict__ out,
    int C, float scale)
{
    int c = blockIdx.x, b = blockIdx.y;
    const u16* p = in + (long)b * bs + (long)c * NP;
    float s = 0.f;
    for (long i = threadIdx.x * 4; i < NP; i += 1024) {
        ushort4 u = *(const ushort4*)(p + i);
        s += bf2f(u.x) + bf2f(u.y) + bf2f(u.z) + bf2f(u.w);
    }
    __shared__ float red[256];
    red[threadIdx.x] = s;
    __syncthreads();
    for (int st = 128; st > 0; st >>= 1) {
        if (threadIdx.x < st) red[threadIdx.x] += red[threadIdx.x + st];
        __syncthreads();
    }
    if (threadIdx.x == 0) out[b * C + c] = red[0] * scale;
}

// stage one LDS row (16 px) of a bf16 channel strip
__device__ __forceinline__ void stage_row(float (*S)[260], const u16* __restrict__ src,
                                          int y0, int j, int px)
{
    int row = y0 - 1 + j;
    if (row >= 0 && row < HHH) {
        ushort8_t a = *(const ushort8_t*)(src + row * WWW + px);
        ushort8_t b = *(const ushort8_t*)(src + row * WWW + px + 8);
#pragma unroll
        for (int e = 0; e < 8; ++e) { S[j][1 + px + e] = bf2f(a[e]); S[j][9 + px + e] = bf2f(b[e]); }
    } else {
#pragma unroll
        for (int e = 0; e < 16; ++e) S[j][1 + px + e] = 0.f;
    }
}
__device__ __forceinline__ float conv9(const float (*S)[260], int r, int col,
                                       const float* __restrict__ w9)
{
    float a = 0.f;
#pragma unroll
    for (int ky = 0; ky < 3; ++ky)
#pragma unroll
        for (int kx = 0; kx < 3; ++kx)
            a = fmaf(w9[ky * 3 + kx], S[r + ky][col + kx], a);
    return a;
}

// depthwise 3x3, 16-row strips. grid (16, C, nb)
__global__ __launch_bounds__(256) void dw3x3_strip(
    const u16* __restrict__ in, long inBS, const float* __restrict__ w,
    u16* __restrict__ out, long outBS)
{
    int strip = blockIdx.x, c = blockIdx.y, b = blockIdx.z;
    int y0 = strip * 16, tid = threadIdx.x;
    __shared__ float S[18][260];
    const u16* src = in + (long)b * inBS + (long)c * NP;
    int j = tid >> 4, px = (tid & 15) * 16;
    stage_row(S, src, y0, j, px);
    if (tid < 32) stage_row(S, src, y0, 16 + (tid >> 4), px);
    if (tid < 18) { S[tid][0] = 0.f; S[tid][257] = 0.f; }
    __syncthreads();
    float w9[9];
#pragma unroll
    for (int k = 0; k < 9; ++k) w9[k] = w[c * 9 + k];
    u16* dst = out + (long)b * outBS + (long)c * NP;
#pragma unroll
    for (int r = 0; r < 16; ++r)
        dst[(y0 + r) * WWW + tid] = f2bf(conv9(S, r, tid, w9));
}

// ffn: dw3x3 on (c, c+128) + gelu(y1)*y2, strips. grid (16, 128, nb)
__global__ __launch_bounds__(256) void ffn_dw_glu_strip(
    const u16* __restrict__ y, long yBS, const float* __restrict__ w,
    u16* __restrict__ g, long gBS)
{
    int strip = blockIdx.x, c = blockIdx.y, b = blockIdx.z;
    int y0 = strip * 16, tid = threadIdx.x;
    __shared__ float S1[18][260];
    __shared__ float S2[18][260];
    const u16* s1 = y + (long)b * yBS + (long)c * NP;
    const u16* s2 = y + (long)b * yBS + (long)(c + 128) * NP;
    int j = tid >> 4, px = (tid & 15) * 16;
    stage_row(S1, s1, y0, j, px);
    if (tid < 32) stage_row(S1, s1, y0, 16 + (tid >> 4), px);
    stage_row(S2, s2, y0, j, px);
    if (tid < 32) stage_row(S2, s2, y0, 16 + (tid >> 4), px);
    if (tid < 18) { S1[tid][0] = S1[tid][257] = 0.f; S2[tid][0] = S2[tid][257] = 0.f; }
    __syncthreads();
    float w1[9], w2[9];
#pragma unroll
    for (int k = 0; k < 9; ++k) { w1[k] = w[c * 9 + k]; w2[k] = w[(c + 128) * 9 + k]; }
    u16* dst = g + (long)b * gBS + (long)c * NP;
#pragma unroll
    for (int r = 0; r < 16; ++r) {
        float a1 = conv9(S1, r, tid, w1);
        float a2 = conv9(S2, r, tid, w2);
        dst[(y0 + r) * WWW + tid] = f2bf(gelu_exact(a1) * a2);
    }
}

// CIIM grouped dw conv, strips. grid (16, 64, nb)
__global__ __launch_bounds__(256) void ciim_dw_strip(
    const u16* __restrict__ fuse, long fBS, const float* __restrict__ means,
    const float* __restrict__ wdw, const float* __restrict__ bdw,
    u16* __restrict__ hl, long hlBS)
{
    int strip = blockIdx.x, c = blockIdx.y, b = blockIdx.z;
    int y0 = strip * 16, tid = threadIdx.x;
    __shared__ float S[18][260];
    float acc[16];
    float bias = bdw[c];
#pragma unroll
    for (int r = 0; r < 16; ++r) acc[r] = bias;
    for (int j6 = 0; j6 < 6; ++j6) {
        int ic = 6 * c + j6;
        const float* w9p = wdw + (c * 6 + j6) * 9;
        float w9[9];
#pragma unroll
        for (int k = 0; k < 9; ++k) w9[k] = w9p[k];
        if (ic < 128) {
            __syncthreads();
            const u16* src = fuse + (long)b * fBS + (long)ic * NP;
            int j = tid >> 4, px = (tid & 15) * 16;
            stage_row(S, src, y0, j, px);
            if (tid < 32) stage_row(S, src, y0, 16 + (tid >> 4), px);
            if (tid < 18) { S[tid][0] = 0.f; S[tid][257] = 0.f; }
            __syncthreads();
#pragma unroll
            for (int r = 0; r < 16; ++r) acc[r] += conv9(S, r, tid, w9);
        } else {
            float mv = means[b * 256 + ic - 128];
#pragma unroll
            for (int r = 0; r < 16; ++r) {
                int row = y0 + r;
                float ws = 0.f;
#pragma unroll
                for (int ky = 0; ky < 3; ++ky) {
                    int yy = row + ky - 1;
                    if (yy < 0 || yy >= HHH) continue;
#pragma unroll
                    for (int kx = 0; kx < 3; ++kx) {
                        int xx = tid + kx - 1;
                        if (xx < 0 || xx >= WWW) continue;
                        ws += w9[ky * 3 + kx];
                    }
                }
                acc[r] += mv * ws;
            }
        }
    }
    u16* dst = hl + (long)b * hlBS + (long)c * NP;
#pragma unroll
    for (int r = 0; r < 16; ++r) dst[(y0 + r) * WWW + tid] = f2bf(acc[r]);
}

// gating + concat + channel shuffle. grid (64, 128, nb)
__global__ __launch_bounds__(256) void outsh4(
    const u16* __restrict__ hl, long hlBS,
    const float* __restrict__ low, long lBS,
    const float* __restrict__ high,
    u16* __restrict__ outb, long oBS)
{
    long p = ((long)blockIdx.x * 256 + threadIdx.x) * 4;
    int cn = blockIdx.y, b = blockIdx.z;
    int co = (cn & 31) * 4 + (cn >> 5);
    const u16* hp;
    const float* sp;
    if (co < 64) {
        hp = hl + (long)b * hlBS + (long)co * NP + p;
        sp = low + (long)b * lBS + (long)co * NP + p;
    } else {
        hp = hl + (long)b * hlBS + (long)(co - 64) * NP + p;
        sp = high + (long)b * lBS + (long)(co - 64) * NP + p;
    }
    ushort4 hu = *(const ushort4*)hp;
    float4 sv = *(const float4*)sp;
    float hv[4] = {bf2f(hu.x), bf2f(hu.y), bf2f(hu.z), bf2f(hu.w)};
    float s4[4] = {sv.x, sv.y, sv.z, sv.w};
    ushort4 ovec;
    u16* ov = (u16*)&ovec;
#pragma unroll
    for (int k = 0; k < 4; ++k) {
        float gg = (co < 64) ? sigmoidf_(gelu_exact(hv[k])) : sigmoidf_(fmaxf(hv[k], 0.f));
        ov[k] = f2bf(gg * s4[k]);
    }
    *(ushort4*)((u16*)outb + (long)b * oBS + (long)cn * NP + p) = ovec;
}

// scaled rc2 weights (bf16). grid (nb*32)
__global__ __launch_bounds__(256) void rc2w_build(
    const float* __restrict__ ecam, const float* __restrict__ ecaw,
    const float* __restrict__ wrc2, u16* __restrict__ wout)
{
    int idx = blockIdx.x * 256 + threadIdx.x;
    int c = idx & 127, o = (idx >> 7) & 63, b = idx >> 13;
    float y = sigmoidf_(ecam[b * 128 + c] * ecaw[c]);
    wout[idx] = f2bf(wrc2[o * 128 + c] * y);
}

// q.k dots + sumsq norms over pixel chunks. grid (QKCH, 8, nb)
__global__ __launch_bounds__(256) void qk_dot(
    const u16* __restrict__ D, long dBS, float* __restrict__ part)
{
    int chunk = blockIdx.x, h = blockIdx.y, b = blockIdx.z;
    int tid = threadIdx.x, lane = tid & 63, wave = tid >> 6;
    const u16* q = D + (long)b * dBS + (long)(h * 8) * NP;
    const u16* k = q + 64 * NP;
    float dots[64], nq[8], nk[8];
#pragma unroll
    for (int a = 0; a < 64; ++a) dots[a] = 0.f;
#pragma unroll
    for (int a = 0; a < 8; ++a) { nq[a] = 0.f; nk[a] = 0.f; }
    long base = (long)chunk * 4096 + tid * 8;
    for (int pass = 0; pass < 2; ++pass) {
        long p = base + pass * 2048;
        ushort8_t qv[8], kv[8];
#pragma unroll
        for (int i = 0; i < 8; ++i) qv[i] = *(const ushort8_t*)(q + (long)i * NP + p);
#pragma unroll
        for (int i = 0; i < 8; ++i) kv[i] = *(const ushort8_t*)(k + (long)i * NP + p);
#pragma unroll
        for (int e = 0; e < 8; ++e) {
            float qe[8], ke[8];
#pragma unroll
            for (int i = 0; i < 8; ++i) { qe[i] = bf2f(qv[i][e]); ke[i] = bf2f(kv[i][e]); }
#pragma unroll
            for (int i = 0; i < 8; ++i) {
                nq[i] = fmaf(qe[i], qe[i], nq[i]);
                nk[i] = fmaf(ke[i], ke[i], nk[i]);
#pragma unroll
                for (int jj = 0; jj < 8; ++jj)
                    dots[i * 8 + jj] = fmaf(qe[i], ke[jj], dots[i * 8 + jj]);
            }
        }
    }
    __shared__ float red[4][80];
#pragma unroll
    for (int a = 0; a < 64; ++a) {
        float v = dots[a];
#pragma unroll
        for (int o = 32; o > 0; o >>= 1) v += __shfl_xor(v, o);
        if (lane == 0) red[wave][a] = v;
    }
#pragma unroll
    for (int a = 0; a < 8; ++a) {
        float v1 = nq[a], v2 = nk[a];
#pragma unroll
        for (int o = 32; o > 0; o >>= 1) { v1 += __shfl_xor(v1, o); v2 += __shfl_xor(v2, o); }
        if (lane == 0) { red[wave][64 + a] = v1; red[wave][72 + a] = v2; }
    }
    __syncthreads();
    if (tid < 80) {
        float v = red[0][tid] + red[1][tid] + red[2][tid] + red[3][tid];
        part[(((long)b * 8 + h) * 80 + tid) * QKCH + chunk] = v;
    }
}

// reduce partials + softmax + Weff (bf16). grid (nb), block 64
__global__ void attn_finalize(
    const float* __restrict__ part, const float* __restrict__ temp,
    const float* __restrict__ wproj, u16* __restrict__ weffb)
{
    int b = blockIdx.x, t = threadIdx.x;
    __shared__ float Sg[8][80];
    __shared__ float att[8][8][8];
    for (int h = 0; h < 8; ++h)
        for (int e = t; e < 80; e += 64) {
            const float* pp = part + (((long)b * 8 + h) * 80 + e) * QKCH;
            float s = 0.f;
#pragma unroll
            for (int c = 0; c < QKCH; ++c) s += pp[c];
            Sg[h][e] = s;
        }
    __syncthreads();
    {
        int h = t >> 3, iq = t & 7;
        float nqv = fmaxf(sqrtf(Sg[h][64 + iq]), 1e-12f);
        float tp = temp[h];
        float row[8], mx = -1e30f;
#pragma unroll
        for (int jj = 0; jj < 8; ++jj) {
            float nkv = fmaxf(sqrtf(Sg[h][72 + jj]), 1e-12f);
            row[jj] = Sg[h][iq * 8 + jj] / (nqv * nkv) * tp;
            mx = fmaxf(mx, row[jj]);
        }
        float sum = 0.f;
#pragma unroll
        for (int jj = 0; jj < 8; ++jj) { row[jj] = __expf(row[jj] - mx); sum += row[jj]; }
        float rinv = 1.f / sum;
#pragma unroll
        for (int jj = 0; jj < 8; ++jj) att[h][iq][jj] = row[jj] * rinv;
    }
    __syncthreads();
    for (int cv = 0; cv < 64; ++cv) {
        int h = cv >> 3, jj = cv & 7;
        float s = 0.f;
#pragma unroll
        for (int i = 0; i < 8; ++i) s = fmaf(wproj[t * 64 + h * 8 + i], att[h][i][jj], s);
        weffb[((long)b * 64 + t) * 64 + cv] = f2bf(s);
    }
}

// head conv1: 3x3, 64->32, leaky. grid (64, 2, nb)
__global__ __launch_bounds__(256) void head_conv1(
    const float* __restrict__ x, const float* __restrict__ w,
    float* __restrict__ out)
{
    int b = blockIdx.z;
    int oBase = blockIdx.y * 16;
    int r = threadIdx.x >> 6;
    int lx = threadIdx.x & 63;
    int y = blockIdx.x * 4 + r;
    int x0 = lx * 4;
    __shared__ float wl[64][9][16];
    for (int idx = threadIdx.x; idx < 64 * 9 * 16; idx += 256) {
        int o = idx & 15, tap = (idx >> 4) % 9, c = idx / 144;
        wl[c][tap][o] = w[((long)(oBase + o) * 64 + c) * 9 + tap];
    }
    __syncthreads();
    float acc[16][4];
#pragma unroll
    for (int o = 0; o < 16; ++o)
#pragma unroll
        for (int px = 0; px < 4; ++px) acc[o][px] = 0.f;
    for (int c = 0; c < 64; ++c) {
        const float* src = x + ((long)b * 64 + c) * NP;
        float row[3][6];
#pragma unroll
        for (int ky = 0; ky < 3; ++ky) {
            int yy = y + ky - 1;
            bool yok = (yy >= 0 && yy < HHH);
#pragma unroll
            for (int dx = 0; dx < 6; ++dx) {
                int xx = x0 + dx - 1;
                row[ky][dx] = (yok && xx >= 0 && xx < WWW) ? src[yy * WWW + xx] : 0.f;
            }
        }
#pragma unroll
        for (int ky = 0; ky < 3; ++ky)
#pragma unroll
            for (int kx = 0; kx < 3; ++kx) {
                int tap = ky * 3 + kx;
#pragma unroll
                for (int px = 0; px < 4; ++px) {
                    float xv = row[ky][kx + px];
#pragma unroll
                    for (int o = 0; o < 16; ++o)
                        acc[o][px] = fmaf(wl[c][tap][o], xv, acc[o][px]);
                }
            }
    }
#pragma unroll
    for (int o = 0; o < 16; ++o) {
        float v[4];
#pragma unroll
        for (int px = 0; px < 4; ++px) {
            float a = acc[o][px];
            v[px] = a > 0.f ? a : 0.01f * a;
        }
        *(float4*)(out + ((long)b * 32 + oBase + o) * NP + y * WWW + x0) =
            make_float4(v[0], v[1], v[2], v[3]);
    }
}

// head conv2: 3x3, 32->1, + inp, sigmoid. grid (256, nb)
__global__ __launch_bounds__(256) void head_conv2(
    const float* __restrict__ x, const float* __restrict__ w,
    const float* __restrict__ inp, float* __restrict__ out)
{
    int xx0 = threadIdx.x, y = blockIdx.x, b = blockIdx.y;
    __shared__ float wl[288];
    for (int idx = threadIdx.x; idx < 288; idx += 256) wl[idx] = w[idx];
    __syncthreads();
    float acc = 0.f;
    for (int c = 0; c < 32; ++c) {
        const float* src = x + ((long)b * 32 + c) * NP;
#pragma unroll
        for (int ky = 0; ky < 3; ++ky) {
            int yy = y + ky - 1;
            if (yy < 0 || yy >= HHH) continue;
#pragma unroll
            for (int kx = 0; kx < 3; ++kx) {
                int xx = xx0 + kx - 1;
                if (xx < 0 || xx >= WWW) continue;
                acc += wl[c * 9 + ky * 3 + kx] * src[yy * WWW + xx];
            }
        }
    }
    float v = acc + inp[(long)b * NP + y * WWW + xx0];
    out[(long)b * NP + y * WWW + xx0] = 1.f / (1.f + expf(-v));
}

// ---------------------------------------------------------------------------
extern "C" void kernel_launch(void* const* d_in, const int* in_sizes, int n_in,
                              void* d_out, int out_size, void* d_ws, size_t ws_size,
                              hipStream_t stream)
{
    const float* inp    = (const float*)d_in[0];
    const float* base   = (const float*)d_in[1];
    const float* detail = (const float*)d_in[2];
    const float* w_ir   = (const float*)d_in[3];
    const float* w_vi   = (const float*)d_in[4];
    const float* w_fu   = (const float*)d_in[5];
    const float* b_fu   = (const float*)d_in[6];
    const float* w_dwc  = (const float*)d_in[7];
    const float* b_dwc  = (const float*)d_in[8];
    const float* eca_w  = (const float*)d_in[9];
    const float* w_rc2  = (const float*)d_in[10];
    const float* ln1w   = (const float*)d_in[11];
    const float* ln1b   = (const float*)d_in[12];
    const float* w_qkv  = (const float*)d_in[13];
    const float* w_qdw  = (const float*)d_in[14];
    const float* temp   = (const float*)d_in[15];
    const float* w_proj = (const float*)d_in[16];
    const float* ln2w   = (const float*)d_in[17];
    const float* ln2b   = (const float*)d_in[18];
    const float* w_in_  = (const float*)d_in[19];
    const float* w_fdw  = (const float*)d_in[20];
    const float* w_out_ = (const float*)d_in[21];
    const float* w_h1   = (const float*)d_in[22];
    const float* w_h2   = (const float*)d_in[23];

    float* out = (float*)d_out;

    auto needB = [&](long nb) -> size_t {
        return (size_t)nb * NP * (64 * 4 + 64 * 2 + 256 * 2 + 192 * 2) + (16u << 20);
    };
    int bInner;
    if (ws_size >= needB(4)) bInner = 4;
    else if (ws_size >= needB(1)) bInner = 1;
    else {
        diag_kernel<<<1, 64, 0, stream>>>(out, (float)(ws_size >> 20));
        return;
    }
    const long nb = bInner;

    char* p = (char*)d_ws;
    auto alloc = [&](size_t bytes) -> char* {
        char* r = p; p += (bytes + 255) & ~(size_t)255; return r;
    };
    float* X      = (float*)alloc((size_t)nb * 64 * NP * 4);
    u16*   XN     = (u16*)alloc((size_t)nb * 64 * NP * 2);
    u16*   Y      = (u16*)alloc((size_t)nb * 256 * NP * 2);
    u16*   Dq     = (u16*)alloc((size_t)nb * 192 * NP * 2);
    float* part   = (float*)alloc((size_t)nb * 8 * 80 * QKCH * 4);
    u16*   weffb  = (u16*)alloc((size_t)nb * 4096 * 2);
    u16*   rc2wb  = (u16*)alloc((size_t)nb * 8192 * 2);
    float* means  = (float*)alloc((size_t)nb * 256 * 4);
    float* ecam   = (float*)alloc((size_t)nb * 128 * 4);
    u16*   fq_bf  = (u16*)alloc((size_t)4 * 192 * 64 * 2);
    float* fqB    = (float*)alloc((size_t)4 * 192 * 4);
    u16*   ff_bf  = (u16*)alloc((size_t)4 * 256 * 64 * 2);
    float* ffB    = (float*)alloc((size_t)4 * 256 * 4);
    u16*   wir_bf = (u16*)alloc(8192 * 2);
    u16*   wvi_bf = (u16*)alloc(8192 * 2);
    u16*   wfu_bf = (u16*)alloc(32768 * 2);
    u16*   wout_bf= (u16*)alloc(32768 * 2);
    float* H32 = (float*)Y;

    dim3 blk(256);

    // one-time weight prep
    fold_ln<<<dim3(28), dim3(64), 0, stream>>>(w_qkv, ln1w, ln1b, w_in_, ln2w, ln2b,
                                               fq_bf, fqB, ff_bf, ffB);
    cvt_f2b<<<dim3(8), blk, 0, stream>>>(w_ir, wir_bf, 8192);
    cvt_f2b<<<dim3(8), blk, 0, stream>>>(w_vi, wvi_bf, 8192);
    cvt_f2b<<<dim3(32), blk, 0, stream>>>(w_fu, wfu_bf, 32768);
    cvt_f2b<<<dim3(32), blk, 0, stream>>>(w_out_, wout_bf, 32768);

    for (int b0 = 0; b0 < 4; b0 += bInner) {
        const float* inpB    = inp + (long)b0 * NP;
        const float* baseB   = base + (long)b0 * 64 * NP;
        const float* detailB = detail + (long)b0 * 64 * NP;
        float* out0  = out + (long)b0 * NP;
        float* outX0 = out + 262144 + (long)b0 * 64 * NP;
        long cvtN = nb * 64 * NP;

        // ---- CIIM ----
        cvt_f2b<<<dim3(cvtN / 1024), blk, 0, stream>>>(baseB, XN, cvtN);
        gemm_mfma<1, 0, 0, 0><<<dim3(2, 256, nb), blk, 0, stream>>>(
            XN, 64 * NP, wir_bf, 0, nullptr, nullptr, 0, Y, 256 * NP, nullptr, 0, 64);
        cvt_f2b<<<dim3(cvtN / 1024), blk, 0, stream>>>(detailB, Dq, cvtN);
        gemm_mfma<1, 0, 0, 0><<<dim3(2, 256, nb), blk, 0, stream>>>(
            Dq, 64 * NP, wvi_bf, 0, nullptr, nullptr, 0, Y + 128 * NP, 256 * NP, nullptr, 0, 64);
        chanreduce_bf<<<dim3(256, nb), blk, 0, stream>>>(Y, 256 * NP, means, 256, 1.f / NP);
        gemm_mfma<1, 0, 0, 1><<<dim3(2, 256, nb), blk, 0, stream>>>(
            Y, 256 * NP, wfu_bf, 0, b_fu, nullptr, 0, Dq, 192 * NP, nullptr, 0, 256);
        ciim_dw_strip<<<dim3(16, 64, nb), blk, 0, stream>>>(
            Dq, 192 * NP, means, w_dwc, b_dwc, XN, 64 * NP);
        outsh4<<<dim3(64, 128, nb), blk, 0, stream>>>(
            XN, 64 * NP, baseB, 64 * NP, detailB, Y, 256 * NP);
        chanreduce_bf<<<dim3(128, nb), blk, 0, stream>>>(Y, 256 * NP, ecam, 128, 1.f / NP);
        rc2w_build<<<dim3(nb * 32), blk, 0, stream>>>(ecam, eca_w, w_rc2, rc2wb);
        gemm_mfma<0, 0, 1, 0><<<dim3(1, 256, nb), blk, 0, stream>>>(
            Y, 256 * NP, rc2wb, 8192, nullptr, nullptr, 0, X, 64 * NP, outX0, 64 * NP, 128);

        // ---- transformer blocks ----
        for (int i = 0; i < 4; ++i) {
            ln_norm<<<dim3(256, nb), blk, 0, stream>>>(X, XN);
            gemm_mfma<1, 0, 0, 1><<<dim3(3, 256, nb), blk, 0, stream>>>(
                XN, 64 * NP, fq_bf + (long)i * 192 * 64, 0, fqB + i * 192,
                nullptr, 0, Y, 256 * NP, nullptr, 0, 64);
            dw3x3_strip<<<dim3(16, 192, nb), blk, 0, stream>>>(
                Y, 256 * NP, w_qdw + (long)i * 192 * 9, Dq, 192 * NP);
            qk_dot<<<dim3(QKCH, 8, nb), blk, 0, stream>>>(Dq, 192 * NP, part);
            attn_finalize<<<dim3(nb), dim3(64), 0, stream>>>(
                part, temp + i * 8, w_proj + (long)i * 4096, weffb);
            gemm_mfma<0, 1, 0, 0><<<dim3(1, 256, nb), blk, 0, stream>>>(
                Dq + 128 * NP, 192 * NP, weffb, 4096, nullptr, X, 64 * NP,
                X, 64 * NP, nullptr, 0, 64);
            ln_norm<<<dim3(256, nb), blk, 0, stream>>>(X, XN);
            gemm_mfma<1, 0, 0, 1><<<dim3(4, 256, nb), blk, 0, stream>>>(
                XN, 64 * NP, ff_bf + (long)i * 256 * 64, 0, ffB + i * 256,
                nullptr, 0, Y, 256 * NP, nullptr, 0, 64);
            ffn_dw_glu_strip<<<dim3(16, 128, nb), blk, 0, stream>>>(
                Y, 256 * NP, w_fdw + (long)i * 256 * 9, Dq, 192 * NP);
            gemm_mfma<0, 1, 0, 0><<<dim3(1, 256, nb), blk, 0, stream>>>(
                Dq, 192 * NP, wout_bf + (long)i * 8192, 0, nullptr, X, 64 * NP,
                X, 64 * NP, nullptr, 0, 128);
        }

        // ---- head ----
        head_conv1<<<dim3(64, 2, nb), blk, 0, stream>>>(X, w_h1, H32);
        head_conv2<<<dim3(256, nb), blk, 0, stream>>>(H32, w_h2, inpB, out0);
    }
}

// Round 5
// 3453.791 us; speedup vs baseline: 2.0273x; 1.0070x over previous
//
#include <hip/hip_runtime.h>
#include <hip/hip_bf16.h>
#include <math.h>

#define NP 65536L
#define HHH 256
#define WWW 256
#define QKCH 16

typedef unsigned short u16;
typedef unsigned short ushort8_t __attribute__((ext_vector_type(8)));
typedef short s16x8 __attribute__((ext_vector_type(8)));
typedef float f32x4 __attribute__((ext_vector_type(4)));

__device__ __forceinline__ float bf2f(u16 u) { return __uint_as_float(((unsigned)u) << 16); }
__device__ __forceinline__ u16 f2bf(float f) {
    __hip_bfloat16 h = __float2bfloat16(f);
    return *reinterpret_cast<u16*>(&h);
}
__device__ __forceinline__ float sigmoidf_(float x) { return 1.f / (1.f + __expf(-x)); }
__device__ __forceinline__ float gelu_exact(float x) {
    return 0.5f * x * (1.f + erff(x * 0.70710678118654752f));
}

__global__ void diag_kernel(float* out, float v) {
    if (threadIdx.x == 0 && blockIdx.x == 0) out[0] = v;
}

// fp32 -> bf16 bulk convert (n multiple of 4; grid = n/1024)
__global__ __launch_bounds__(256) void cvt_f2b(const float* __restrict__ src,
                                               u16* __restrict__ dst, long n)
{
    long i = ((long)blockIdx.x * 256 + threadIdx.x) * 4;
    if (i >= n) return;
    float4 v = *(const float4*)(src + i);
    ushort4 o;
    o.x = f2bf(v.x); o.y = f2bf(v.y); o.z = f2bf(v.z); o.w = f2bf(v.w);
    *(ushort4*)(dst + i) = o;
}

// ---------------------------------------------------------------------------
// MFMA bf16 GEMM for 1x1 conv: out[b][o][p] = sum_c w[o][c] * in[b][c][p]
// block: 256 thr = 4 waves; tile M=64 o x N=256 px; K chunks of 64.
// LDS: XT transposed [px][c] (pad 8) so B-frag = one ds_read_b128.
// grid (M/64, 256, nb)
// ---------------------------------------------------------------------------
template<int OUT_BF16, int RESID, int DUAL, int BIAS>
__global__ __launch_bounds__(256) void gemm_mfma(
    const u16* __restrict__ in, long inBS,
    const u16* __restrict__ wbf, long wBS,
    const float* __restrict__ bias,
    const float* __restrict__ resid, long resBS,
    void* __restrict__ outp, long outBS,
    float* __restrict__ out2, long out2BS,
    int Cin)
{
    __shared__ u16 XT[256][72];
    __shared__ u16 WT[64][72];
    int b = blockIdx.z;
    int oBase = blockIdx.x * 64;
    long P0 = (long)blockIdx.y * 256;
    int tid = threadIdx.x;
    int lane = tid & 63, wave = tid >> 6;
    const u16* inB = in + (long)b * inBS;
    const u16* wB = wbf + (long)b * wBS;

    f32x4 acc[4][4];
#pragma unroll
    for (int m = 0; m < 4; ++m)
#pragma unroll
        for (int n = 0; n < 4; ++n) acc[m][n] = (f32x4){0.f, 0.f, 0.f, 0.f};

    for (int ck = 0; ck < Cin; ck += 64) {
        if (ck) __syncthreads();
        {   // stage weights chunk [64 o][64 c]
            int o = tid >> 2, cs = (tid & 3) * 16;
            const u16* src = wB + (long)(oBase + o) * Cin + ck + cs;
            ushort8_t w0 = *(const ushort8_t*)src;
            ushort8_t w1 = *(const ushort8_t*)(src + 8);
            *(ushort8_t*)&WT[o][cs] = w0;
            *(ushort8_t*)&WT[o][cs + 8] = w1;
        }
        {   // stage X chunk transposed: [256 px][64 c]
            int c0 = (tid & 7) * 8;
            int pt = (tid >> 3) * 8;
            ushort8_t r[8];
#pragma unroll
            for (int i = 0; i < 8; ++i)
                r[i] = *(const ushort8_t*)(inB + (long)(ck + c0 + i) * NP + P0 + pt);
#pragma unroll
            for (int j = 0; j < 8; ++j) {
                ushort8_t v;
#pragma unroll
                for (int i = 0; i < 8; ++i) v[i] = r[i][j];
                *(ushort8_t*)&XT[pt + j][c0] = v;
            }
        }
        __syncthreads();
        int rl = lane & 15;
#pragma unroll
        for (int ks = 0; ks < 2; ++ks) {
            int kc = ks * 32 + (lane >> 4) * 8;
            s16x8 a[4], bb[4];
#pragma unroll
            for (int m = 0; m < 4; ++m)
                a[m] = *(const s16x8*)&WT[m * 16 + rl][kc];
#pragma unroll
            for (int n = 0; n < 4; ++n)
                bb[n] = *(const s16x8*)&XT[wave * 64 + n * 16 + rl][kc];
#pragma unroll
            for (int m = 0; m < 4; ++m)
#pragma unroll
                for (int n = 0; n < 4; ++n)
                    acc[m][n] = __builtin_amdgcn_mfma_f32_16x16x32_bf16(
                        a[m], bb[n], acc[m][n], 0, 0, 0);
        }
    }
    // epilogue: D col = lane&15 (pixel), row = (lane>>4)*4 + reg (o)
    int rl = lane & 15, rg = lane >> 4;
#pragma unroll
    for (int m = 0; m < 4; ++m) {
        int o0 = oBase + m * 16 + rg * 4;
#pragma unroll
        for (int n = 0; n < 4; ++n) {
            long px = P0 + wave * 64 + n * 16 + rl;
#pragma unroll
            for (int r = 0; r < 4; ++r) {
                int oo = o0 + r;
                float v = acc[m][n][r];
                if (BIAS) v += bias[oo];
                if (RESID) v += resid[(long)b * resBS + (long)oo * NP + px];
                if (OUT_BF16) ((u16*)outp)[(long)b * outBS + (long)oo * NP + px] = f2bf(v);
                else ((float*)outp)[(long)b * outBS + (long)oo * NP + px] = v;
                if (DUAL) out2[(long)b * out2BS + (long)oo * NP + px] = v;
            }
        }
    }
}

// LN standardize pre-pass: XN = (X - mu)/sqrt(var+eps), bf16. grid (256, nb)
__global__ __launch_bounds__(256) void ln_norm(
    const float* __restrict__ X, u16* __restrict__ XN)
{
    int b = blockIdx.y;
    long p = (long)blockIdx.x * 256 + threadIdx.x;
    const float* xb = X + (long)b * 64 * NP + p;
    float x[64];
    float s = 0.f, s2 = 0.f;
#pragma unroll
    for (int c = 0; c < 64; ++c) {
        x[c] = xb[(long)c * NP];
        s += x[c]; s2 = fmaf(x[c], x[c], s2);
    }
    float mu = s * (1.f / 64.f);
    float var = fmaxf(s2 * (1.f / 64.f) - mu * mu, 0.f);
    float inv = rsqrtf(var + 1e-5f);
    u16* xo = XN + (long)b * 64 * NP + p;
#pragma unroll
    for (int c = 0; c < 64; ++c) xo[(long)c * NP] = f2bf((x[c] - mu) * inv);
}

// fold LN gamma/beta into qkv / ffn-in weights; bf16 weights + fp32 bias.
__global__ void fold_ln(
    const float* __restrict__ wqkv, const float* __restrict__ ln1w, const float* __restrict__ ln1b,
    const float* __restrict__ win,  const float* __restrict__ ln2w, const float* __restrict__ ln2b,
    u16* __restrict__ fq, float* __restrict__ fqB,
    u16* __restrict__ ff, float* __restrict__ ffB)
{
    int g = blockIdx.x;
    int i = g / 7, r = g % 7;
    const float *wsrc, *lg, *lb;
    u16* wd; float* Bd;
    int obase;
    if (r < 3) {
        wsrc = wqkv + (long)i * 192 * 64; lg = ln1w + i * 64; lb = ln1b + i * 64;
        wd = fq + (long)i * 192 * 64; Bd = fqB + i * 192; obase = r * 64;
    } else {
        wsrc = win + (long)i * 256 * 64; lg = ln2w + i * 64; lb = ln2b + i * 64;
        wd = ff + (long)i * 256 * 64; Bd = ffB + i * 256; obase = (r - 3) * 64;
    }
    int o = obase + threadIdx.x;
    float Bv = 0.f;
    for (int c = 0; c < 64; ++c) {
        float wv = wsrc[(long)o * 64 + c];
        wd[(long)o * 64 + c] = f2bf(wv * lg[c]);
        Bv += wv * lb[c];
    }
    Bd[o] = Bv;
}

// per-(b,c) mean of bf16 buffer. grid (C, nb)
__global__ __launch_bounds__(256) void chanreduce_bf(
    const u16* __restrict__ in, long bs, float* __restrict__ out,
    int C, float scale)
{
    int c = blockIdx.x, b = blockIdx.y;
    const u16* p = in + (long)b * bs + (long)c * NP;
    float s = 0.f;
    for (long i = threadIdx.x * 4; i < NP; i += 1024) {
        ushort4 u = *(const ushort4*)(p + i);
        s += bf2f(u.x) + bf2f(u.y) + bf2f(u.z) + bf2f(u.w);
    }
    __shared__ float red[256];
    red[threadIdx.x] = s;
    __syncthreads();
    for (int st = 128; st > 0; st >>= 1) {
        if (threadIdx.x < st) red[threadIdx.x] += red[threadIdx.x + st];
        __syncthreads();
    }
    if (threadIdx.x == 0) out[b * C + c] = red[0] * scale;
}

// stage one LDS row (16 px) of a bf16 channel strip
__device__ __forceinline__ void stage_row(float (*S)[260], const u16* __restrict__ src,
                                          int y0, int j, int px)
{
    int row = y0 - 1 + j;
    if (row >= 0 && row < HHH) {
        ushort8_t a = *(const ushort8_t*)(src + row * WWW + px);
        ushort8_t b = *(const ushort8_t*)(src + row * WWW + px + 8);
#pragma unroll
        for (int e = 0; e < 8; ++e) { S[j][1 + px + e] = bf2f(a[e]); S[j][9 + px + e] = bf2f(b[e]); }
    } else {
#pragma unroll
        for (int e = 0; e < 16; ++e) S[j][1 + px + e] = 0.f;
    }
}
__device__ __forceinline__ float conv9(const float (*S)[260], int r, int col,
                                       const float* __restrict__ w9)
{
    float a = 0.f;
#pragma unroll
    for (int ky = 0; ky < 3; ++ky)
#pragma unroll
        for (int kx = 0; kx < 3; ++kx)
            a = fmaf(w9[ky * 3 + kx], S[r + ky][col + kx], a);
    return a;
}

// depthwise 3x3, 16-row strips. grid (16, C, nb)
__global__ __launch_bounds__(256) void dw3x3_strip(
    const u16* __restrict__ in, long inBS, const float* __restrict__ w,
    u16* __restrict__ out, long outBS)
{
    int strip = blockIdx.x, c = blockIdx.y, b = blockIdx.z;
    int y0 = strip * 16, tid = threadIdx.x;
    __shared__ float S[18][260];
    const u16* src = in + (long)b * inBS + (long)c * NP;
    int j = tid >> 4, px = (tid & 15) * 16;
    stage_row(S, src, y0, j, px);
    if (tid < 32) stage_row(S, src, y0, 16 + (tid >> 4), px);
    if (tid < 18) { S[tid][0] = 0.f; S[tid][257] = 0.f; }
    __syncthreads();
    float w9[9];
#pragma unroll
    for (int k = 0; k < 9; ++k) w9[k] = w[c * 9 + k];
    u16* dst = out + (long)b * outBS + (long)c * NP;
#pragma unroll
    for (int r = 0; r < 16; ++r)
        dst[(y0 + r) * WWW + tid] = f2bf(conv9(S, r, tid, w9));
}

// ffn: dw3x3 on (c, c+128) + gelu(y1)*y2, strips. grid (16, 128, nb)
__global__ __launch_bounds__(256) void ffn_dw_glu_strip(
    const u16* __restrict__ y, long yBS, const float* __restrict__ w,
    u16* __restrict__ g, long gBS)
{
    int strip = blockIdx.x, c = blockIdx.y, b = blockIdx.z;
    int y0 = strip * 16, tid = threadIdx.x;
    __shared__ float S1[18][260];
    __shared__ float S2[18][260];
    const u16* s1 = y + (long)b * yBS + (long)c * NP;
    const u16* s2 = y + (long)b * yBS + (long)(c + 128) * NP;
    int j = tid >> 4, px = (tid & 15) * 16;
    stage_row(S1, s1, y0, j, px);
    if (tid < 32) stage_row(S1, s1, y0, 16 + (tid >> 4), px);
    stage_row(S2, s2, y0, j, px);
    if (tid < 32) stage_row(S2, s2, y0, 16 + (tid >> 4), px);
    if (tid < 18) { S1[tid][0] = S1[tid][257] = 0.f; S2[tid][0] = S2[tid][257] = 0.f; }
    __syncthreads();
    float w1[9], w2[9];
#pragma unroll
    for (int k = 0; k < 9; ++k) { w1[k] = w[c * 9 + k]; w2[k] = w[(c + 128) * 9 + k]; }
    u16* dst = g + (long)b * gBS + (long)c * NP;
#pragma unroll
    for (int r = 0; r < 16; ++r) {
        float a1 = conv9(S1, r, tid, w1);
        float a2 = conv9(S2, r, tid, w2);
        dst[(y0 + r) * WWW + tid] = f2bf(gelu_exact(a1) * a2);
    }
}

// CIIM grouped dw conv, strips. grid (16, 64, nb)
__global__ __launch_bounds__(256) void ciim_dw_strip(
    const u16* __restrict__ fuse, long fBS, const float* __restrict__ means,
    const float* __restrict__ wdw, const float* __restrict__ bdw,
    u16* __restrict__ hl, long hlBS)
{
    int strip = blockIdx.x, c = blockIdx.y, b = blockIdx.z;
    int y0 = strip * 16, tid = threadIdx.x;
    __shared__ float S[18][260];
    float acc[16];
    float bias = bdw[c];
#pragma unroll
    for (int r = 0; r < 16; ++r) acc[r] = bias;
    for (int j6 = 0; j6 < 6; ++j6) {
        int ic = 6 * c + j6;
        const float* w9p = wdw + (c * 6 + j6) * 9;
        float w9[9];
#pragma unroll
        for (int k = 0; k < 9; ++k) w9[k] = w9p[k];
        if (ic < 128) {
            __syncthreads();
            const u16* src = fuse + (long)b * fBS + (long)ic * NP;
            int j = tid >> 4, px = (tid & 15) * 16;
            stage_row(S, src, y0, j, px);
            if (tid < 32) stage_row(S, src, y0, 16 + (tid >> 4), px);
            if (tid < 18) { S[tid][0] = 0.f; S[tid][257] = 0.f; }
            __syncthreads();
#pragma unroll
            for (int r = 0; r < 16; ++r) acc[r] += conv9(S, r, tid, w9);
        } else {
            float mv = means[b * 256 + ic - 128];
#pragma unroll
            for (int r = 0; r < 16; ++r) {
                int row = y0 + r;
                float ws = 0.f;
#pragma unroll
                for (int ky = 0; ky < 3; ++ky) {
                    int yy = row + ky - 1;
                    if (yy < 0 || yy >= HHH) continue;
#pragma unroll
                    for (int kx = 0; kx < 3; ++kx) {
                        int xx = tid + kx - 1;
                        if (xx < 0 || xx >= WWW) continue;
                        ws += w9[ky * 3 + kx];
                    }
                }
                acc[r] += mv * ws;
            }
        }
    }
    u16* dst = hl + (long)b * hlBS + (long)c * NP;
#pragma unroll
    for (int r = 0; r < 16; ++r) dst[(y0 + r) * WWW + tid] = f2bf(acc[r]);
}

// gating + concat + channel shuffle. grid (64, 128, nb)
__global__ __launch_bounds__(256) void outsh4(
    const u16* __restrict__ hl, long hlBS,
    const float* __restrict__ low, long lBS,
    const float* __restrict__ high,
    u16* __restrict__ outb, long oBS)
{
    long p = ((long)blockIdx.x * 256 + threadIdx.x) * 4;
    int cn = blockIdx.y, b = blockIdx.z;
    int co = (cn & 31) * 4 + (cn >> 5);
    const u16* hp;
    const float* sp;
    if (co < 64) {
        hp = hl + (long)b * hlBS + (long)co * NP + p;
        sp = low + (long)b * lBS + (long)co * NP + p;
    } else {
        hp = hl + (long)b * hlBS + (long)(co - 64) * NP + p;
        sp = high + (long)b * lBS + (long)(co - 64) * NP + p;
    }
    ushort4 hu = *(const ushort4*)hp;
    float4 sv = *(const float4*)sp;
    float hv[4] = {bf2f(hu.x), bf2f(hu.y), bf2f(hu.z), bf2f(hu.w)};
    float s4[4] = {sv.x, sv.y, sv.z, sv.w};
    ushort4 ovec;
    u16* ov = (u16*)&ovec;
#pragma unroll
    for (int k = 0; k < 4; ++k) {
        float gg = (co < 64) ? sigmoidf_(gelu_exact(hv[k])) : sigmoidf_(fmaxf(hv[k], 0.f));
        ov[k] = f2bf(gg * s4[k]);
    }
    *(ushort4*)((u16*)outb + (long)b * oBS + (long)cn * NP + p) = ovec;
}

// scaled rc2 weights (bf16). grid (nb*32)
__global__ __launch_bounds__(256) void rc2w_build(
    const float* __restrict__ ecam, const float* __restrict__ ecaw,
    const float* __restrict__ wrc2, u16* __restrict__ wout)
{
    int idx = blockIdx.x * 256 + threadIdx.x;
    int c = idx & 127, o = (idx >> 7) & 63, b = idx >> 13;
    float y = sigmoidf_(ecam[b * 128 + c] * ecaw[c]);
    wout[idx] = f2bf(wrc2[o * 128 + c] * y);
}

// q.k dots + sumsq norms over pixel chunks. grid (QKCH, 8, nb)
__global__ __launch_bounds__(256) void qk_dot(
    const u16* __restrict__ D, long dBS, float* __restrict__ part)
{
    int chunk = blockIdx.x, h = blockIdx.y, b = blockIdx.z;
    int tid = threadIdx.x, lane = tid & 63, wave = tid >> 6;
    const u16* q = D + (long)b * dBS + (long)(h * 8) * NP;
    const u16* k = q + 64 * NP;
    float dots[64], nq[8], nk[8];
#pragma unroll
    for (int a = 0; a < 64; ++a) dots[a] = 0.f;
#pragma unroll
    for (int a = 0; a < 8; ++a) { nq[a] = 0.f; nk[a] = 0.f; }
    long base = (long)chunk * 4096 + tid * 8;
    for (int pass = 0; pass < 2; ++pass) {
        long p = base + pass * 2048;
        ushort8_t qv[8], kv[8];
#pragma unroll
        for (int i = 0; i < 8; ++i) qv[i] = *(const ushort8_t*)(q + (long)i * NP + p);
#pragma unroll
        for (int i = 0; i < 8; ++i) kv[i] = *(const ushort8_t*)(k + (long)i * NP + p);
#pragma unroll
        for (int e = 0; e < 8; ++e) {
            float qe[8], ke[8];
#pragma unroll
            for (int i = 0; i < 8; ++i) { qe[i] = bf2f(qv[i][e]); ke[i] = bf2f(kv[i][e]); }
#pragma unroll
            for (int i = 0; i < 8; ++i) {
                nq[i] = fmaf(qe[i], qe[i], nq[i]);
                nk[i] = fmaf(ke[i], ke[i], nk[i]);
#pragma unroll
                for (int jj = 0; jj < 8; ++jj)
                    dots[i * 8 + jj] = fmaf(qe[i], ke[jj], dots[i * 8 + jj]);
            }
        }
    }
    __shared__ float red[4][80];
#pragma unroll
    for (int a = 0; a < 64; ++a) {
        float v = dots[a];
#pragma unroll
        for (int o = 32; o > 0; o >>= 1) v += __shfl_xor(v, o);
        if (lane == 0) red[wave][a] = v;
    }
#pragma unroll
    for (int a = 0; a < 8; ++a) {
        float v1 = nq[a], v2 = nk[a];
#pragma unroll
        for (int o = 32; o > 0; o >>= 1) { v1 += __shfl_xor(v1, o); v2 += __shfl_xor(v2, o); }
        if (lane == 0) { red[wave][64 + a] = v1; red[wave][72 + a] = v2; }
    }
    __syncthreads();
    if (tid < 80) {
        float v = red[0][tid] + red[1][tid] + red[2][tid] + red[3][tid];
        part[(((long)b * 8 + h) * 80 + tid) * QKCH + chunk] = v;
    }
}

// reduce partials + softmax + Weff (bf16). grid (nb), block 64
__global__ void attn_finalize(
    const float* __restrict__ part, const float* __restrict__ temp,
    const float* __restrict__ wproj, u16* __restrict__ weffb)
{
    int b = blockIdx.x, t = threadIdx.x;
    __shared__ float Sg[8][80];
    __shared__ float att[8][8][8];
    for (int h = 0; h < 8; ++h)
        for (int e = t; e < 80; e += 64) {
            const float* pp = part + (((long)b * 8 + h) * 80 + e) * QKCH;
            float s = 0.f;
#pragma unroll
            for (int c = 0; c < QKCH; ++c) s += pp[c];
            Sg[h][e] = s;
        }
    __syncthreads();
    {
        int h = t >> 3, iq = t & 7;
        float nqv = fmaxf(sqrtf(Sg[h][64 + iq]), 1e-12f);
        float tp = temp[h];
        float row[8], mx = -1e30f;
#pragma unroll
        for (int jj = 0; jj < 8; ++jj) {
            float nkv = fmaxf(sqrtf(Sg[h][72 + jj]), 1e-12f);
            row[jj] = Sg[h][iq * 8 + jj] / (nqv * nkv) * tp;
            mx = fmaxf(mx, row[jj]);
        }
        float sum = 0.f;
#pragma unroll
        for (int jj = 0; jj < 8; ++jj) { row[jj] = __expf(row[jj] - mx); sum += row[jj]; }
        float rinv = 1.f / sum;
#pragma unroll
        for (int jj = 0; jj < 8; ++jj) att[h][iq][jj] = row[jj] * rinv;
    }
    __syncthreads();
    for (int cv = 0; cv < 64; ++cv) {
        int h = cv >> 3, jj = cv & 7;
        float s = 0.f;
#pragma unroll
        for (int i = 0; i < 8; ++i) s = fmaf(wproj[t * 64 + h * 8 + i], att[h][i][jj], s);
        weffb[((long)b * 64 + t) * 64 + cv] = f2bf(s);
    }
}

// head conv1: 3x3, 64->32, leaky. grid (64, 2, nb)
__global__ __launch_bounds__(256) void head_conv1(
    const float* __restrict__ x, const float* __restrict__ w,
    float* __restrict__ out)
{
    int b = blockIdx.z;
    int oBase = blockIdx.y * 16;
    int r = threadIdx.x >> 6;
    int lx = threadIdx.x & 63;
    int y = blockIdx.x * 4 + r;
    int x0 = lx * 4;
    __shared__ float wl[64][9][16];
    for (int idx = threadIdx.x; idx < 64 * 9 * 16; idx += 256) {
        int o = idx & 15, tap = (idx >> 4) % 9, c = idx / 144;
        wl[c][tap][o] = w[((long)(oBase + o) * 64 + c) * 9 + tap];
    }
    __syncthreads();
    float acc[16][4];
#pragma unroll
    for (int o = 0; o < 16; ++o)
#pragma unroll
        for (int px = 0; px < 4; ++px) acc[o][px] = 0.f;
    for (int c = 0; c < 64; ++c) {
        const float* src = x + ((long)b * 64 + c) * NP;
        float row[3][6];
#pragma unroll
        for (int ky = 0; ky < 3; ++ky) {
            int yy = y + ky - 1;
            bool yok = (yy >= 0 && yy < HHH);
#pragma unroll
            for (int dx = 0; dx < 6; ++dx) {
                int xx = x0 + dx - 1;
                row[ky][dx] = (yok && xx >= 0 && xx < WWW) ? src[yy * WWW + xx] : 0.f;
            }
        }
#pragma unroll
        for (int ky = 0; ky < 3; ++ky)
#pragma unroll
            for (int kx = 0; kx < 3; ++kx) {
                int tap = ky * 3 + kx;
#pragma unroll
                for (int px = 0; px < 4; ++px) {
                    float xv = row[ky][kx + px];
#pragma unroll
                    for (int o = 0; o < 16; ++o)
                        acc[o][px] = fmaf(wl[c][tap][o], xv, acc[o][px]);
                }
            }
    }
#pragma unroll
    for (int o = 0; o < 16; ++o) {
        float v[4];
#pragma unroll
        for (int px = 0; px < 4; ++px) {
            float a = acc[o][px];
            v[px] = a > 0.f ? a : 0.01f * a;
        }
        *(float4*)(out + ((long)b * 32 + oBase + o) * NP + y * WWW + x0) =
            make_float4(v[0], v[1], v[2], v[3]);
    }
}

// head conv2: 3x3, 32->1, + inp, sigmoid. grid (256, nb)
__global__ __launch_bounds__(256) void head_conv2(
    const float* __restrict__ x, const float* __restrict__ w,
    const float* __restrict__ inp, float* __restrict__ out)
{
    int xx0 = threadIdx.x, y = blockIdx.x, b = blockIdx.y;
    __shared__ float wl[288];
    for (int idx = threadIdx.x; idx < 288; idx += 256) wl[idx] = w[idx];
    __syncthreads();
    float acc = 0.f;
    for (int c = 0; c < 32; ++c) {
        const float* src = x + ((long)b * 32 + c) * NP;
#pragma unroll
        for (int ky = 0; ky < 3; ++ky) {
            int yy = y + ky - 1;
            if (yy < 0 || yy >= HHH) continue;
#pragma unroll
            for (int kx = 0; kx < 3; ++kx) {
                int xx = xx0 + kx - 1;
                if (xx < 0 || xx >= WWW) continue;
                acc += wl[c * 9 + ky * 3 + kx] * src[yy * WWW + xx];
            }
        }
    }
    float v = acc + inp[(long)b * NP + y * WWW + xx0];
    out[(long)b * NP + y * WWW + xx0] = 1.f / (1.f + expf(-v));
}

// ---------------------------------------------------------------------------
extern "C" void kernel_launch(void* const* d_in, const int* in_sizes, int n_in,
                              void* d_out, int out_size, void* d_ws, size_t ws_size,
                              hipStream_t stream)
{
    const float* inp    = (const float*)d_in[0];
    const float* base   = (const float*)d_in[1];
    const float* detail = (const float*)d_in[2];
    const float* w_ir   = (const float*)d_in[3];
    const float* w_vi   = (const float*)d_in[4];
    const float* w_fu   = (const float*)d_in[5];
    const float* b_fu   = (const float*)d_in[6];
    const float* w_dwc  = (const float*)d_in[7];
    const float* b_dwc  = (const float*)d_in[8];
    const float* eca_w  = (const float*)d_in[9];
    const float* w_rc2  = (const float*)d_in[10];
    const float* ln1w   = (const float*)d_in[11];
    const float* ln1b   = (const float*)d_in[12];
    const float* w_qkv  = (const float*)d_in[13];
    const float* w_qdw  = (const float*)d_in[14];
    const float* temp   = (const float*)d_in[15];
    const float* w_proj = (const float*)d_in[16];
    const float* ln2w   = (const float*)d_in[17];
    const float* ln2b   = (const float*)d_in[18];
    const float* w_in_  = (const float*)d_in[19];
    const float* w_fdw  = (const float*)d_in[20];
    const float* w_out_ = (const float*)d_in[21];
    const float* w_h1   = (const float*)d_in[22];
    const float* w_h2   = (const float*)d_in[23];

    float* out = (float*)d_out;

    auto needB = [&](long nb) -> size_t {
        return (size_t)nb * NP * (64 * 4 + 64 * 2 + 256 * 2 + 192 * 2) + (16u << 20);
    };
    int bInner;
    if (ws_size >= needB(4)) bInner = 4;
    else if (ws_size >= needB(1)) bInner = 1;
    else {
        diag_kernel<<<1, 64, 0, stream>>>(out, (float)(ws_size >> 20));
        return;
    }
    const long nb = bInner;

    char* p = (char*)d_ws;
    auto alloc = [&](size_t bytes) -> char* {
        char* r = p; p += (bytes + 255) & ~(size_t)255; return r;
    };
    float* X      = (float*)alloc((size_t)nb * 64 * NP * 4);
    u16*   XN     = (u16*)alloc((size_t)nb * 64 * NP * 2);
    u16*   Y      = (u16*)alloc((size_t)nb * 256 * NP * 2);
    u16*   Dq     = (u16*)alloc((size_t)nb * 192 * NP * 2);
    float* part   = (float*)alloc((size_t)nb * 8 * 80 * QKCH * 4);
    u16*   weffb  = (u16*)alloc((size_t)nb * 4096 * 2);
    u16*   rc2wb  = (u16*)alloc((size_t)nb * 8192 * 2);
    float* means  = (float*)alloc((size_t)nb * 256 * 4);
    float* ecam   = (float*)alloc((size_t)nb * 128 * 4);
    u16*   fq_bf  = (u16*)alloc((size_t)4 * 192 * 64 * 2);
    float* fqB    = (float*)alloc((size_t)4 * 192 * 4);
    u16*   ff_bf  = (u16*)alloc((size_t)4 * 256 * 64 * 2);
    float* ffB    = (float*)alloc((size_t)4 * 256 * 4);
    u16*   wir_bf = (u16*)alloc(8192 * 2);
    u16*   wvi_bf = (u16*)alloc(8192 * 2);
    u16*   wfu_bf = (u16*)alloc(32768 * 2);
    u16*   wout_bf= (u16*)alloc(32768 * 2);
    float* H32 = (float*)Y;

    dim3 blk(256);

    // one-time weight prep
    fold_ln<<<dim3(28), dim3(64), 0, stream>>>(w_qkv, ln1w, ln1b, w_in_, ln2w, ln2b,
                                               fq_bf, fqB, ff_bf, ffB);
    cvt_f2b<<<dim3(8), blk, 0, stream>>>(w_ir, wir_bf, 8192);
    cvt_f2b<<<dim3(8), blk, 0, stream>>>(w_vi, wvi_bf, 8192);
    cvt_f2b<<<dim3(32), blk, 0, stream>>>(w_fu, wfu_bf, 32768);
    cvt_f2b<<<dim3(32), blk, 0, stream>>>(w_out_, wout_bf, 32768);

    for (int b0 = 0; b0 < 4; b0 += bInner) {
        const float* inpB    = inp + (long)b0 * NP;
        const float* baseB   = base + (long)b0 * 64 * NP;
        const float* detailB = detail + (long)b0 * 64 * NP;
        float* out0  = out + (long)b0 * NP;
        float* outX0 = out + 262144 + (long)b0 * 64 * NP;
        long cvtN = nb * 64 * NP;

        // ---- CIIM ----
        cvt_f2b<<<dim3(cvtN / 1024), blk, 0, stream>>>(baseB, XN, cvtN);
        gemm_mfma<1, 0, 0, 0><<<dim3(2, 256, nb), blk, 0, stream>>>(
            XN, 64 * NP, wir_bf, 0, nullptr, nullptr, 0, Y, 256 * NP, nullptr, 0, 64);
        cvt_f2b<<<dim3(cvtN / 1024), blk, 0, stream>>>(detailB, Dq, cvtN);
        gemm_mfma<1, 0, 0, 0><<<dim3(2, 256, nb), blk, 0, stream>>>(
            Dq, 64 * NP, wvi_bf, 0, nullptr, nullptr, 0, Y + 128 * NP, 256 * NP, nullptr, 0, 64);
        chanreduce_bf<<<dim3(256, nb), blk, 0, stream>>>(Y, 256 * NP, means, 256, 1.f / NP);
        gemm_mfma<1, 0, 0, 1><<<dim3(2, 256, nb), blk, 0, stream>>>(
            Y, 256 * NP, wfu_bf, 0, b_fu, nullptr, 0, Dq, 192 * NP, nullptr, 0, 256);
        ciim_dw_strip<<<dim3(16, 64, nb), blk, 0, stream>>>(
            Dq, 192 * NP, means, w_dwc, b_dwc, XN, 64 * NP);
        outsh4<<<dim3(64, 128, nb), blk, 0, stream>>>(
            XN, 64 * NP, baseB, 64 * NP, detailB, Y, 256 * NP);
        chanreduce_bf<<<dim3(128, nb), blk, 0, stream>>>(Y, 256 * NP, ecam, 128, 1.f / NP);
        rc2w_build<<<dim3(nb * 32), blk, 0, stream>>>(ecam, eca_w, w_rc2, rc2wb);
        gemm_mfma<0, 0, 1, 0><<<dim3(1, 256, nb), blk, 0, stream>>>(
            Y, 256 * NP, rc2wb, 8192, nullptr, nullptr, 0, X, 64 * NP, outX0, 64 * NP, 128);

        // ---- transformer blocks ----
        for (int i = 0; i < 4; ++i) {
            ln_norm<<<dim3(256, nb), blk, 0, stream>>>(X, XN);
            gemm_mfma<1, 0, 0, 1><<<dim3(3, 256, nb), blk, 0, stream>>>(
                XN, 64 * NP, fq_bf + (long)i * 192 * 64, 0, fqB + i * 192,
                nullptr, 0, Y, 256 * NP, nullptr, 0, 64);
            dw3x3_strip<<<dim3(16, 192, nb), blk, 0, stream>>>(
                Y, 256 * NP, w_qdw + (long)i * 192 * 9, Dq, 192 * NP);
            qk_dot<<<dim3(QKCH, 8, nb), blk, 0, stream>>>(Dq, 192 * NP, part);
            attn_finalize<<<dim3(nb), dim3(64), 0, stream>>>(
                part, temp + i * 8, w_proj + (long)i * 4096, weffb);
            gemm_mfma<0, 1, 0, 0><<<dim3(1, 256, nb), blk, 0, stream>>>(
                Dq + 128 * NP, 192 * NP, weffb, 4096, nullptr, X, 64 * NP,
                X, 64 * NP, nullptr, 0, 64);
            ln_norm<<<dim3(256, nb), blk, 0, stream>>>(X, XN);
            gemm_mfma<1, 0, 0, 1><<<dim3(4, 256, nb), blk, 0, stream>>>(
                XN, 64 * NP, ff_bf + (long)i * 256 * 64, 0, ffB + i * 256,
                nullptr, 0, Y, 256 * NP, nullptr, 0, 64);
            ffn_dw_glu_strip<<<dim3(16, 128, nb), blk, 0, stream>>>(
                Y, 256 * NP, w_fdw + (long)i * 256 * 9, Dq, 192 * NP);
            gemm_mfma<0, 1, 0, 0><<<dim3(1, 256, nb), blk, 0, stream>>>(
                Dq, 192 * NP, wout_bf + (long)i * 8192, 0, nullptr, X, 64 * NP,
                X, 64 * NP, nullptr, 0, 128);
        }

        // ---- head ----
        head_conv1<<<dim3(64, 2, nb), blk, 0, stream>>>(X, w_h1, H32);
        head_conv2<<<dim3(256, nb), blk, 0, stream>>>(H32, w_h2, inpB, out0);
    }
}